// Round 7
// baseline (447.126 us; speedup 1.0000x reference)
//
#include <hip/hip_runtime.h>
#include <hip/hip_bf16.h>

typedef unsigned short u16;
typedef unsigned int u32;
typedef __bf16 bf16x8 __attribute__((ext_vector_type(8)));
typedef float f32x4 __attribute__((ext_vector_type(4)));

#define DIM 128
#define LDSB 40   // padded LDS row stride in u16 (80 B = 20 words → even bank spread)

__device__ __forceinline__ float bf2f(u16 v) { return __uint_as_float(((u32)v) << 16); }
__device__ __forceinline__ u16 f2bf_rne(float x) {   // inputs known-finite
  u32 u = __float_as_uint(x);
  return (u16)((u + 0x7fffu + ((u >> 16) & 1u)) >> 16);
}
__device__ __forceinline__ float lrelu(float x) { return x > 0.f ? x : 0.01f * x; }
__device__ __forceinline__ int iclamp(int v, int hi) { return v < 0 ? 0 : (v >= hi ? hi - 1 : v); }
__device__ __forceinline__ float sane(float x) { return (x == x) ? x : 0.f; }

__device__ __forceinline__ float wred_max(float v) {
  #pragma unroll
  for (int o = 32; o > 0; o >>= 1) v = fmaxf(v, __shfl_xor(v, o, 64));
  return v;
}

// ---------------- CSR build ----------------
__global__ void hist_k(const int* __restrict__ dst, int* __restrict__ cnt, int E, int N) {
  int e = blockIdx.x * blockDim.x + threadIdx.x;
  if (e < E) {
    int d = dst[e];
    if (d >= 0 && d < N) atomicAdd(&cnt[d], 1);
  }
}

__global__ __launch_bounds__(1024) void scan_k(const int* __restrict__ cnt,
                                               int* __restrict__ offs, int N) {
  __shared__ int sums[1024];
  int t = threadIdx.x;
  int chunk = (N + 1023) >> 10;
  int base = t * chunk;
  int s = 0;
  for (int i = 0; i < chunk; ++i) { int idx = base + i; if (idx < N) s += cnt[idx]; }
  sums[t] = s;
  __syncthreads();
  for (int off = 1; off < 1024; off <<= 1) {
    int v = (t >= off) ? sums[t - off] : 0;
    __syncthreads();
    sums[t] += v;
    __syncthreads();
  }
  int prefix = (t > 0) ? sums[t - 1] : 0;
  for (int i = 0; i < chunk; ++i) {
    int idx = base + i;
    if (idx < N) { offs[idx] = prefix; prefix += cnt[idx]; }
  }
  if (t == 1023) offs[N] = sums[1023];
}

__global__ void scatter_k(const int* __restrict__ dst, const int* __restrict__ offs,
                          int* __restrict__ cursor, int* __restrict__ eid, int E, int N) {
  int e = blockIdx.x * blockDim.x + threadIdx.x;
  if (e < E) {
    int d = dst[e];
    if (d >= 0 && d < N) {
      int pos = offs[d] + atomicAdd(&cursor[d], 1);
      if (pos >= 0 && pos < E) eid[pos] = e;
    }
  }
}

// ---------------- weight prep → combined bf16 B[256][K] (rows 0-127 = D, 128-255 = S)
__global__ void prep_wc2(const float* __restrict__ W1, const float* __restrict__ Wmod,
                         int K, u16* __restrict__ out) {
  int k = blockIdx.x * blockDim.x + threadIdx.x;
  int o = blockIdx.y;                       // 0..255
  if (k >= K) return;
  int half = (o >= 128) ? 128 : 0;
  int oo = o & 127;
  float acc = 0.f;
  for (int i = 0; i < 128; ++i)
    acc += W1[oo * 384 + half + i] * Wmod[i * K + k];
  out[(size_t)o * K + k] = f2bf_rne(acc);
}

__global__ void copy_w1b(const float* __restrict__ W1, u16* __restrict__ out) {
  int k = threadIdx.x;                      // 128
  int o = blockIdx.x;                       // 256
  int half = (o >= 128) ? 128 : 0;
  int oo = o & 127;
  out[o * 128 + k] = f2bf_rne(W1[oo * 384 + half + k]);
}

// Pr[r][o] (bf16) + qr[r] (f32), one block per relation
__global__ __launch_bounds__(128) void prep_pr_q(
    const float* __restrict__ rel, const float* __restrict__ W1,
    const float* __restrict__ b1, const float* __restrict__ bmod,
    const float* __restrict__ w2,
    u16* __restrict__ Pr, float* __restrict__ qr, int NR) {
  __shared__ float red[128];
  int r = blockIdx.x;
  if (r >= NR) return;
  int o = threadIdx.x;
  float acc = b1[o];
  for (int i = 0; i < 128; ++i)
    acc += W1[o * 384 + 256 + i] * rel[r * 128 + i];
  if (bmod != nullptr) {
    for (int i = 0; i < 128; ++i)
      acc += (W1[o * 384 + i] + W1[o * 384 + 128 + i]) * bmod[i];
  }
  Pr[(size_t)r * 128 + o] = f2bf_rne(acc);
  red[o] = acc * w2[o];
  __syncthreads();
  for (int s = 64; s > 0; s >>= 1) {
    if (o < s) red[o] += red[o + s];
    __syncthreads();
  }
  if (o == 0) qr[r] = sane(red[0]);
}

// ---------------- MFMA GEMM: [Pd|Ps][M,128](bf16) = A[M,K](f32→bf16) @ B[256,K]^T
// q{d,s}[n] = f32 row · w2 fused.  Tile: 16 rows × 256 cols per block (625 blocks),
// 4 waves; wave wv → 16 rows × 64 cols (4 MFMA tiles).  LDS rows padded to LDSB.
// C/D layout (verified): col = lane&15, row = (lane>>4)*4 + reg
__global__ __launch_bounds__(256) void gemm2_mfma(
    const float* __restrict__ A, const u16* __restrict__ Bbf,
    const float* __restrict__ w2,
    u16* __restrict__ Pd, u16* __restrict__ Ps,
    float* __restrict__ qd, float* __restrict__ qs,
    int M, int K) {
  __shared__ u16 Asb[16 * LDSB];     // 1.25 KB
  __shared__ u16 Bsb[256 * LDSB];    // 20 KB
  __shared__ float qpart[4][16];
  int tid = threadIdx.x;
  int lane = tid & 63, wv = tid >> 6;
  int quad = lane >> 4, l16 = lane & 15;
  int row0 = blockIdx.x * 16;

  f32x4 acc[4];
  #pragma unroll
  for (int t = 0; t < 4; ++t) acc[t] = (f32x4){0.f, 0.f, 0.f, 0.f};

  // A staging map: thread t → row t>>4 (0..15), k-offset (t&15)*2 (2 f32 each)
  int arow = tid >> 4, akoff = (tid & 15) * 2;
  int garow = row0 + arow;
  if (garow >= M) garow = M - 1;            // safe dup loads; stores guarded
  const float* Ab = A + (size_t)garow * K;
  const u16* Bg = Bbf + (size_t)tid * K;    // thread tid stages B row tid

  for (int k0 = 0; k0 < K; k0 += 32) {
    __syncthreads();
    float2 av = *reinterpret_cast<const float2*>(Ab + k0 + akoff);
    *reinterpret_cast<u32*>(&Asb[arow * LDSB + akoff]) =
        (u32)f2bf_rne(av.x) | ((u32)f2bf_rne(av.y) << 16);
    const uint4* bgp = reinterpret_cast<const uint4*>(Bg + k0);
    uint4* bl = reinterpret_cast<uint4*>(&Bsb[tid * LDSB]);
    bl[0] = bgp[0]; bl[1] = bgp[1]; bl[2] = bgp[2]; bl[3] = bgp[3];
    __syncthreads();

    bf16x8 a = *reinterpret_cast<const bf16x8*>(&Asb[l16 * LDSB + quad * 8]);
    #pragma unroll
    for (int t = 0; t < 4; ++t) {
      bf16x8 b = *reinterpret_cast<const bf16x8*>(
          &Bsb[(wv * 64 + t * 16 + l16) * LDSB + quad * 8]);
      acc[t] = __builtin_amdgcn_mfma_f32_16x16x32_bf16(a, b, acc[t], 0, 0, 0);
    }
  }

  // epilogue: col c = wv*64 + t*16 + l16 (0..255); row = row0 + quad*4 + r
  float w2c[4];
  #pragma unroll
  for (int t = 0; t < 4; ++t) w2c[t] = w2[(wv & 1) * 64 + t * 16 + l16];

  float part[4];
  #pragma unroll
  for (int r = 0; r < 4; ++r) {
    int rr = row0 + quad * 4 + r;
    bool ok = rr < M;
    float qp = 0.f;
    #pragma unroll
    for (int t = 0; t < 4; ++t) {
      int c = (wv & 1) * 64 + t * 16 + l16;
      if (ok) {
        if (wv < 2) Pd[(size_t)rr * 128 + c] = f2bf_rne(acc[t][r]);
        else        Ps[(size_t)rr * 128 + c] = f2bf_rne(acc[t][r]);
      }
      qp += acc[t][r] * w2c[t];
    }
    #pragma unroll
    for (int mk = 1; mk < 16; mk <<= 1) qp += __shfl_xor(qp, mk, 64);
    part[r] = qp;
  }
  if (l16 == 0) {
    #pragma unroll
    for (int r = 0; r < 4; ++r) qpart[wv][quad * 4 + r] = part[r];
  }
  __syncthreads();
  if (tid < 32) {
    int row = tid & 15;
    int rr = row0 + row;
    if (rr < M) {
      if (tid < 16) qd[rr] = sane(qpart[0][row] + qpart[1][row]);
      else          qs[rr] = sane(qpart[2][row] + qpart[3][row]);
    }
  }
}

// ---------------- per-node softmax + aggregation for ONE modality → f32 out ----
__global__ __launch_bounds__(256) void aggregate_m(
    const int* __restrict__ eid, const int* __restrict__ offs,
    const int* __restrict__ src, const int* __restrict__ etyp,
    const float* __restrict__ qd, const float* __restrict__ qs, const float* __restrict__ qr,
    const u16* __restrict__ Pd, const u16* __restrict__ Ps, const u16* __restrict__ Pr,
    const float* __restrict__ alphaP, const float* __restrict__ gammaP,
    int mIdx, int first,
    float* __restrict__ outp,
    int N, int NR, int E) {
  int n = blockIdx.x * 4 + (threadIdx.x >> 6);
  if (n >= N) return;
  int lane = threadIdx.x & 63;
  int eb = offs[n], ee = offs[n + 1];
  if (eb < 0) eb = 0;
  if (eb > E) eb = E;
  if (ee < eb) ee = eb;
  if (ee > E) ee = E;
  int En = ee - eb;

  float al = alphaP[0];
  if (!(al > 0.f && al < 1.f)) al = 0.1f;
  float ga = gammaP[0];
  if (!(ga > 0.f && ga < 1.f)) ga = 0.8f;
  float coef = (mIdx == 0) ? (1.f - al - ga) : (mIdx == 1 ? al : ga);

  float qdn = sane(qd[n]);

  // pass 1: segment max
  float mx = -1e30f;
  for (int i = lane; i < En; i += 64) {
    int e = iclamp(eid[eb + i], E);
    int s = iclamp(src[e], N);
    int t = iclamp(etyp[e], NR);
    mx = fmaxf(mx, lrelu(qdn + sane(qs[s]) + sane(qr[t])));
  }
  mx = wred_max(mx);

  // pass 2 (fused): z and unnormalized accumulation; lane covers dims 2l,2l+1
  float z = 0.f, a0 = 0.f, a1 = 0.f;
  for (int c0 = 0; c0 < En; c0 += 64) {
    int cn = min(64, En - c0);
    float wraw = 0.f;
    int s = 0, t = 0;
    if (lane < cn) {
      int e = iclamp(eid[eb + c0 + lane], E);
      s = iclamp(src[e], N);
      t = iclamp(etyp[e], NR);
      float b = lrelu(qdn + sane(qs[s]) + sane(qr[t]));
      float arg = fmaxf(fminf(b - mx, 0.f), -80.f);
      wraw = __expf(arg);
    }
    z += wraw;
    for (int j = 0; j < cn; ++j) {
      float wj = __shfl(wraw, j, 64);
      int sj = __shfl(s, j, 64);
      int tj = __shfl(t, j, 64);
      u32 pu = *reinterpret_cast<const u32*>(Ps + (size_t)sj * 128 + 2 * lane);
      u32 ru = *reinterpret_cast<const u32*>(Pr + (size_t)tj * 128 + 2 * lane);
      float ps0 = __uint_as_float(pu << 16), ps1 = __uint_as_float(pu & 0xffff0000u);
      float pr0 = __uint_as_float(ru << 16), pr1 = __uint_as_float(ru & 0xffff0000u);
      a0 = fmaf(wj, sane(ps0) + sane(pr0), a0);
      a1 = fmaf(wj, sane(ps1) + sane(pr1), a1);
    }
  }
  #pragma unroll
  for (int o = 32; o > 0; o >>= 1) z += __shfl_xor(z, o, 64);

  float h0 = 0.f, h1 = 0.f;
  if (En > 0 && z > 0.f) {
    float rz = 1.f / z;
    u32 du = *reinterpret_cast<const u32*>(Pd + (size_t)n * 128 + 2 * lane);
    float pd0 = __uint_as_float(du << 16), pd1 = __uint_as_float(du & 0xffff0000u);
    h0 = lrelu(sane(pd0) + a0 * rz);
    h1 = lrelu(sane(pd1) + a1 * rz);
  }
  float c0v = sane(coef * h0);
  float c1v = sane(coef * h1);

  float* op = outp + (size_t)n * 128 + 2 * lane;
  if (first) {
    op[0] = c0v;
    op[1] = c1v;
  } else {
    op[0] = sane(op[0]) + c0v;
    op[1] = sane(op[1]) + c1v;
  }
}

extern "C" void kernel_launch(void* const* d_in, const int* in_sizes, int n_in,
                              void* d_out, int out_size, void* d_ws, size_t ws_size,
                              hipStream_t stream) {
  const int* ei        = (const int*)d_in[1];
  const int* et        = (const int*)d_in[2];
  const float* visual  = (const float*)d_in[3];
  const float* textual = (const float*)d_in[4];
  const float* semb    = (const float*)d_in[5];
  const float* relemb  = (const float*)d_in[6];
  const float* W1s = (const float*)d_in[7];
  const float* b1s = (const float*)d_in[8];
  const float* w2s = (const float*)d_in[9];
  const float* W1v = (const float*)d_in[10];
  const float* b1v = (const float*)d_in[11];
  const float* w2v = (const float*)d_in[12];
  const float* W1t = (const float*)d_in[13];
  const float* b1t = (const float*)d_in[14];
  const float* w2t = (const float*)d_in[15];
  const float* Wv  = (const float*)d_in[16];
  const float* bv  = (const float*)d_in[17];
  const float* Wt  = (const float*)d_in[18];
  const float* bt  = (const float*)d_in[19];
  const float* alphaP = (const float*)d_in[20];
  const float* gammaP = (const float*)d_in[21];
  float* outp = (float*)d_out;

  const int E   = in_sizes[2];
  const int N   = in_sizes[5] / DIM;
  const int NR  = in_sizes[6] / DIM;
  const int VIS = in_sizes[3] / N;   // 512
  const int TXT = in_sizes[4] / N;   // 768
  const int KMAX = (TXT > VIS) ? TXT : VIS;

  // ---- workspace layout (metadata first), gated on ws_size ----
  size_t off = 0;
  auto take = [&](size_t bytes) -> size_t {
    size_t o = off;
    off = (off + bytes + 255) & ~(size_t)255;
    return o;
  };
  size_t o_cnt  = take((size_t)2 * N * 4);
  size_t o_offs = take((size_t)(N + 1) * 4);
  size_t o_eid  = take((size_t)E * 4);
  size_t o_qd   = take((size_t)N * 4);
  size_t o_qs   = take((size_t)N * 4);
  size_t o_qr   = take((size_t)NR * 4);
  size_t o_Pr   = take((size_t)NR * 128 * 2);
  size_t o_Wc   = take((size_t)256 * KMAX * 2);   // combined bf16 B [256][K]
  size_t o_Pd   = take((size_t)N * 128 * 2);
  size_t o_Ps   = take((size_t)N * 128 * 2);
  size_t need   = off;   // ~6.9 MB (proven resident)

  if (ws_size < need) {
    hipMemsetAsync(d_out, 0, (size_t)out_size * 4, stream);  // finite diagnostic
    return;
  }

  char* w = (char*)d_ws;
  int* counts = (int*)(w + o_cnt);
  int* cursor = counts + N;
  int* offs   = (int*)(w + o_offs);
  int* eid    = (int*)(w + o_eid);
  float* qd   = (float*)(w + o_qd);
  float* qs   = (float*)(w + o_qs);
  float* qr   = (float*)(w + o_qr);
  u16* Pr     = (u16*)(w + o_Pr);
  u16* Wc     = (u16*)(w + o_Wc);
  u16* Pd     = (u16*)(w + o_Pd);
  u16* Ps     = (u16*)(w + o_Ps);

  const int* esrc = ei;
  const int* edst = ei + E;

  hipMemsetAsync(counts, 0, (size_t)2 * N * 4, stream);
  hipMemsetAsync(eid, 0, (size_t)E * 4, stream);

  int egrid = (E + 255) / 256;
  hist_k<<<egrid, 256, 0, stream>>>(edst, counts, E, N);
  scan_k<<<1, 1024, 0, stream>>>(counts, offs, N);
  scatter_k<<<egrid, 256, 0, stream>>>(edst, offs, cursor, eid, E, N);

  int gemmGrid = (N + 15) / 16;

  for (int m = 0; m < 3; ++m) {
    const float *W1, *b1, *w2, *Amod, *Wmod, *bmod;
    int K;
    if (m == 0)      { W1 = W1s; b1 = b1s; w2 = w2s; Amod = semb;    Wmod = nullptr; bmod = nullptr; K = DIM; }
    else if (m == 1) { W1 = W1v; b1 = b1v; w2 = w2v; Amod = visual;  Wmod = Wv;      bmod = bv;      K = VIS; }
    else             { W1 = W1t; b1 = b1t; w2 = w2t; Amod = textual; Wmod = Wt;      bmod = bt;      K = TXT; }

    if (m == 0) {
      copy_w1b<<<256, 128, 0, stream>>>(W1, Wc);
    } else {
      prep_wc2<<<dim3((K + 255) / 256, 256), 256, 0, stream>>>(W1, Wmod, K, Wc);
    }
    prep_pr_q<<<NR, 128, 0, stream>>>(relemb, W1, b1, bmod, w2, Pr, qr, NR);

    gemm2_mfma<<<gemmGrid, 256, 0, stream>>>(Amod, Wc, w2, Pd, Ps, qd, qs, N, K);

    aggregate_m<<<(N + 3) / 4, 256, 0, stream>>>(eid, offs, esrc, et,
                                                 qd, qs, qr, Pd, Ps, Pr,
                                                 alphaP, gammaP, m, (m == 0) ? 1 : 0,
                                                 outp, N, NR, E);
  }
}

// Round 8
// 446.482 us; speedup vs baseline: 1.0014x; 1.0014x over previous
//
#include <hip/hip_runtime.h>
#include <hip/hip_bf16.h>

typedef unsigned short u16;
typedef unsigned int u32;
typedef __bf16 bf16x8 __attribute__((ext_vector_type(8)));
typedef float f32x4 __attribute__((ext_vector_type(4)));

#define DIM 128

__device__ __forceinline__ float bf2f(u16 v) { return __uint_as_float(((u32)v) << 16); }
__device__ __forceinline__ u16 f2bf_rne(float x) {   // inputs known-finite
  u32 u = __float_as_uint(x);
  return (u16)((u + 0x7fffu + ((u >> 16) & 1u)) >> 16);
}
__device__ __forceinline__ float lrelu(float x) { return x > 0.f ? x : 0.01f * x; }
__device__ __forceinline__ int iclamp(int v, int hi) { return v < 0 ? 0 : (v >= hi ? hi - 1 : v); }
__device__ __forceinline__ float sane(float x) { return (x == x) ? x : 0.f; }

__device__ __forceinline__ float wred_max(float v) {
  #pragma unroll
  for (int o = 32; o > 0; o >>= 1) v = fmaxf(v, __shfl_xor(v, o, 64));
  return v;
}

// ---------------- CSR build ----------------
__global__ void hist_k(const int* __restrict__ dst, int* __restrict__ cnt, int E, int N) {
  int e = blockIdx.x * blockDim.x + threadIdx.x;
  if (e < E) {
    int d = dst[e];
    if (d >= 0 && d < N) atomicAdd(&cnt[d], 1);
  }
}

__global__ __launch_bounds__(1024) void scan_k(const int* __restrict__ cnt,
                                               int* __restrict__ offs, int N) {
  __shared__ int sums[1024];
  int t = threadIdx.x;
  int chunk = (N + 1023) >> 10;
  int base = t * chunk;
  int s = 0;
  for (int i = 0; i < chunk; ++i) { int idx = base + i; if (idx < N) s += cnt[idx]; }
  sums[t] = s;
  __syncthreads();
  for (int off = 1; off < 1024; off <<= 1) {
    int v = (t >= off) ? sums[t - off] : 0;
    __syncthreads();
    sums[t] += v;
    __syncthreads();
  }
  int prefix = (t > 0) ? sums[t - 1] : 0;
  for (int i = 0; i < chunk; ++i) {
    int idx = base + i;
    if (idx < N) { offs[idx] = prefix; prefix += cnt[idx]; }
  }
  if (t == 1023) offs[N] = sums[1023];
}

__global__ void scatter_k(const int* __restrict__ dst, const int* __restrict__ offs,
                          int* __restrict__ cursor, int* __restrict__ eid, int E, int N) {
  int e = blockIdx.x * blockDim.x + threadIdx.x;
  if (e < E) {
    int d = dst[e];
    if (d >= 0 && d < N) {
      int pos = offs[d] + atomicAdd(&cursor[d], 1);
      if (pos >= 0 && pos < E) eid[pos] = e;
    }
  }
}

// ---------------- weight prep → combined bf16 B[256][K] (rows 0-127 = D, 128-255 = S)
__global__ void prep_wc2(const float* __restrict__ W1, const float* __restrict__ Wmod,
                         int K, u16* __restrict__ out) {
  int k = blockIdx.x * blockDim.x + threadIdx.x;
  int o = blockIdx.y;                       // 0..255
  if (k >= K) return;
  int half = (o >= 128) ? 128 : 0;
  int oo = o & 127;
  float acc = 0.f;
  for (int i = 0; i < 128; ++i)
    acc += W1[oo * 384 + half + i] * Wmod[i * K + k];
  out[(size_t)o * K + k] = f2bf_rne(acc);
}

__global__ void copy_w1b(const float* __restrict__ W1, u16* __restrict__ out) {
  int k = threadIdx.x;                      // 128
  int o = blockIdx.x;                       // 256
  int half = (o >= 128) ? 128 : 0;
  int oo = o & 127;
  out[o * 128 + k] = f2bf_rne(W1[oo * 384 + half + k]);
}

// Pr[r][o] (bf16) + qr[r] (f32), one block per relation
__global__ __launch_bounds__(128) void prep_pr_q(
    const float* __restrict__ rel, const float* __restrict__ W1,
    const float* __restrict__ b1, const float* __restrict__ bmod,
    const float* __restrict__ w2,
    u16* __restrict__ Pr, float* __restrict__ qr, int NR) {
  __shared__ float red[128];
  int r = blockIdx.x;
  if (r >= NR) return;
  int o = threadIdx.x;
  float acc = b1[o];
  for (int i = 0; i < 128; ++i)
    acc += W1[o * 384 + 256 + i] * rel[r * 128 + i];
  if (bmod != nullptr) {
    for (int i = 0; i < 128; ++i)
      acc += (W1[o * 384 + i] + W1[o * 384 + 128 + i]) * bmod[i];
  }
  Pr[(size_t)r * 128 + o] = f2bf_rne(acc);
  red[o] = acc * w2[o];
  __syncthreads();
  for (int s = 64; s > 0; s >>= 1) {
    if (o < s) red[o] += red[o + s];
    __syncthreads();
  }
  if (o == 0) qr[r] = sane(red[0]);
}

// ---------------- barrier-free MFMA GEMM (no LDS staging):
// [Pd|Ps][M,128](bf16) = A[M,K](f32→bf16) @ B[256,K]^T,  q{d,s} fused.
// grid = M/16 blocks × 4 waves; wave wv: rows row0..+16, cols wv*64..+64.
// A-frag: lane(l16,quad) = A[row0+l16][k0+quad*8 ..+8) (2×float4 → bf16x8).
// B-frag: direct global bf16x8 at Bbf[(wv*64+t*16+l16)*K + k0+quad*8] (L2-hot).
// C/D layout (verified): col = lane&15, row = (lane>>4)*4 + reg
__global__ __launch_bounds__(256) void gemm3_mfma(
    const float* __restrict__ A, const u16* __restrict__ Bbf,
    const float* __restrict__ w2,
    u16* __restrict__ Pd, u16* __restrict__ Ps,
    float* __restrict__ qd, float* __restrict__ qs,
    int M, int K) {
  __shared__ float qpart[4][16];
  int tid = threadIdx.x;
  int lane = tid & 63, wv = tid >> 6;
  int quad = lane >> 4, l16 = lane & 15;
  int row0 = blockIdx.x * 16;

  int arow = row0 + l16;
  if (arow >= M) arow = M - 1;              // safe dup loads; stores guarded
  const float* Ap = A + (size_t)arow * K + quad * 8;
  const u16* Bp0 = Bbf + (size_t)(wv * 64 + 0  + l16) * K + quad * 8;
  const u16* Bp1 = Bbf + (size_t)(wv * 64 + 16 + l16) * K + quad * 8;
  const u16* Bp2 = Bbf + (size_t)(wv * 64 + 32 + l16) * K + quad * 8;
  const u16* Bp3 = Bbf + (size_t)(wv * 64 + 48 + l16) * K + quad * 8;

  f32x4 acc[4];
  #pragma unroll
  for (int t = 0; t < 4; ++t) acc[t] = (f32x4){0.f, 0.f, 0.f, 0.f};

  union { bf16x8 v; u32 w[4]; } af;

  // K % 64 == 0 for all modalities (128/512/768): unroll 2 k-steps per trip
  for (int k0 = 0; k0 < K; k0 += 64) {
    #pragma unroll
    for (int u = 0; u < 2; ++u) {
      int kk = k0 + u * 32;
      float4 v0 = *reinterpret_cast<const float4*>(Ap + kk);
      float4 v1 = *reinterpret_cast<const float4*>(Ap + kk + 4);
      af.w[0] = (u32)f2bf_rne(v0.x) | ((u32)f2bf_rne(v0.y) << 16);
      af.w[1] = (u32)f2bf_rne(v0.z) | ((u32)f2bf_rne(v0.w) << 16);
      af.w[2] = (u32)f2bf_rne(v1.x) | ((u32)f2bf_rne(v1.y) << 16);
      af.w[3] = (u32)f2bf_rne(v1.z) | ((u32)f2bf_rne(v1.w) << 16);
      bf16x8 b0 = *reinterpret_cast<const bf16x8*>(Bp0 + kk);
      bf16x8 b1 = *reinterpret_cast<const bf16x8*>(Bp1 + kk);
      bf16x8 b2 = *reinterpret_cast<const bf16x8*>(Bp2 + kk);
      bf16x8 b3 = *reinterpret_cast<const bf16x8*>(Bp3 + kk);
      acc[0] = __builtin_amdgcn_mfma_f32_16x16x32_bf16(af.v, b0, acc[0], 0, 0, 0);
      acc[1] = __builtin_amdgcn_mfma_f32_16x16x32_bf16(af.v, b1, acc[1], 0, 0, 0);
      acc[2] = __builtin_amdgcn_mfma_f32_16x16x32_bf16(af.v, b2, acc[2], 0, 0, 0);
      acc[3] = __builtin_amdgcn_mfma_f32_16x16x32_bf16(af.v, b3, acc[3], 0, 0, 0);
    }
  }

  // epilogue: global col = wv*64 + t*16 + l16; local col c = (wv&1)*64 + t*16 + l16
  float w2c[4];
  #pragma unroll
  for (int t = 0; t < 4; ++t) w2c[t] = w2[(wv & 1) * 64 + t * 16 + l16];

  float part[4];
  #pragma unroll
  for (int r = 0; r < 4; ++r) {
    int rr = row0 + quad * 4 + r;
    bool ok = rr < M;
    float qp = 0.f;
    #pragma unroll
    for (int t = 0; t < 4; ++t) {
      int c = (wv & 1) * 64 + t * 16 + l16;
      if (ok) {
        if (wv < 2) Pd[(size_t)rr * 128 + c] = f2bf_rne(acc[t][r]);
        else        Ps[(size_t)rr * 128 + c] = f2bf_rne(acc[t][r]);
      }
      qp += acc[t][r] * w2c[t];
    }
    #pragma unroll
    for (int mk = 1; mk < 16; mk <<= 1) qp += __shfl_xor(qp, mk, 64);
    part[r] = qp;
  }
  if (l16 == 0) {
    #pragma unroll
    for (int r = 0; r < 4; ++r) qpart[wv][quad * 4 + r] = part[r];
  }
  __syncthreads();
  if (tid < 32) {
    int row = tid & 15;
    int rr = row0 + row;
    if (rr < M) {
      if (tid < 16) qd[rr] = sane(qpart[0][row] + qpart[1][row]);
      else          qs[rr] = sane(qpart[2][row] + qpart[3][row]);
    }
  }
}

// ---------------- per-node softmax + aggregation for ONE modality → f32 out ----
__global__ __launch_bounds__(256) void aggregate_m(
    const int* __restrict__ eid, const int* __restrict__ offs,
    const int* __restrict__ src, const int* __restrict__ etyp,
    const float* __restrict__ qd, const float* __restrict__ qs, const float* __restrict__ qr,
    const u16* __restrict__ Pd, const u16* __restrict__ Ps, const u16* __restrict__ Pr,
    const float* __restrict__ alphaP, const float* __restrict__ gammaP,
    int mIdx, int first,
    float* __restrict__ outp,
    int N, int NR, int E) {
  int n = blockIdx.x * 4 + (threadIdx.x >> 6);
  if (n >= N) return;
  int lane = threadIdx.x & 63;
  int eb = offs[n], ee = offs[n + 1];
  if (eb < 0) eb = 0;
  if (eb > E) eb = E;
  if (ee < eb) ee = eb;
  if (ee > E) ee = E;
  int En = ee - eb;

  float al = alphaP[0];
  if (!(al > 0.f && al < 1.f)) al = 0.1f;
  float ga = gammaP[0];
  if (!(ga > 0.f && ga < 1.f)) ga = 0.8f;
  float coef = (mIdx == 0) ? (1.f - al - ga) : (mIdx == 1 ? al : ga);

  float qdn = sane(qd[n]);

  // pass 1: segment max
  float mx = -1e30f;
  for (int i = lane; i < En; i += 64) {
    int e = iclamp(eid[eb + i], E);
    int s = iclamp(src[e], N);
    int t = iclamp(etyp[e], NR);
    mx = fmaxf(mx, lrelu(qdn + sane(qs[s]) + sane(qr[t])));
  }
  mx = wred_max(mx);

  // pass 2 (fused): z and unnormalized accumulation; lane covers dims 2l,2l+1
  float z = 0.f, a0 = 0.f, a1 = 0.f;
  for (int c0 = 0; c0 < En; c0 += 64) {
    int cn = min(64, En - c0);
    float wraw = 0.f;
    int s = 0, t = 0;
    if (lane < cn) {
      int e = iclamp(eid[eb + c0 + lane], E);
      s = iclamp(src[e], N);
      t = iclamp(etyp[e], NR);
      float b = lrelu(qdn + sane(qs[s]) + sane(qr[t]));
      float arg = fmaxf(fminf(b - mx, 0.f), -80.f);
      wraw = __expf(arg);
    }
    z += wraw;
    for (int j = 0; j < cn; ++j) {
      float wj = __shfl(wraw, j, 64);
      int sj = __shfl(s, j, 64);
      int tj = __shfl(t, j, 64);
      u32 pu = *reinterpret_cast<const u32*>(Ps + (size_t)sj * 128 + 2 * lane);
      u32 ru = *reinterpret_cast<const u32*>(Pr + (size_t)tj * 128 + 2 * lane);
      float ps0 = __uint_as_float(pu << 16), ps1 = __uint_as_float(pu & 0xffff0000u);
      float pr0 = __uint_as_float(ru << 16), pr1 = __uint_as_float(ru & 0xffff0000u);
      a0 = fmaf(wj, sane(ps0) + sane(pr0), a0);
      a1 = fmaf(wj, sane(ps1) + sane(pr1), a1);
    }
  }
  #pragma unroll
  for (int o = 32; o > 0; o >>= 1) z += __shfl_xor(z, o, 64);

  float h0 = 0.f, h1 = 0.f;
  if (En > 0 && z > 0.f) {
    float rz = 1.f / z;
    u32 du = *reinterpret_cast<const u32*>(Pd + (size_t)n * 128 + 2 * lane);
    float pd0 = __uint_as_float(du << 16), pd1 = __uint_as_float(du & 0xffff0000u);
    h0 = lrelu(sane(pd0) + a0 * rz);
    h1 = lrelu(sane(pd1) + a1 * rz);
  }
  float c0v = sane(coef * h0);
  float c1v = sane(coef * h1);

  float* op = outp + (size_t)n * 128 + 2 * lane;
  if (first) {
    op[0] = c0v;
    op[1] = c1v;
  } else {
    op[0] = sane(op[0]) + c0v;
    op[1] = sane(op[1]) + c1v;
  }
}

extern "C" void kernel_launch(void* const* d_in, const int* in_sizes, int n_in,
                              void* d_out, int out_size, void* d_ws, size_t ws_size,
                              hipStream_t stream) {
  const int* ei        = (const int*)d_in[1];
  const int* et        = (const int*)d_in[2];
  const float* visual  = (const float*)d_in[3];
  const float* textual = (const float*)d_in[4];
  const float* semb    = (const float*)d_in[5];
  const float* relemb  = (const float*)d_in[6];
  const float* W1s = (const float*)d_in[7];
  const float* b1s = (const float*)d_in[8];
  const float* w2s = (const float*)d_in[9];
  const float* W1v = (const float*)d_in[10];
  const float* b1v = (const float*)d_in[11];
  const float* w2v = (const float*)d_in[12];
  const float* W1t = (const float*)d_in[13];
  const float* b1t = (const float*)d_in[14];
  const float* w2t = (const float*)d_in[15];
  const float* Wv  = (const float*)d_in[16];
  const float* bv  = (const float*)d_in[17];
  const float* Wt  = (const float*)d_in[18];
  const float* bt  = (const float*)d_in[19];
  const float* alphaP = (const float*)d_in[20];
  const float* gammaP = (const float*)d_in[21];
  float* outp = (float*)d_out;

  const int E   = in_sizes[2];
  const int N   = in_sizes[5] / DIM;
  const int NR  = in_sizes[6] / DIM;
  const int VIS = in_sizes[3] / N;   // 512
  const int TXT = in_sizes[4] / N;   // 768
  const int KMAX = (TXT > VIS) ? TXT : VIS;

  // ---- workspace layout (metadata first), gated on ws_size ----
  size_t off = 0;
  auto take = [&](size_t bytes) -> size_t {
    size_t o = off;
    off = (off + bytes + 255) & ~(size_t)255;
    return o;
  };
  size_t o_cnt  = take((size_t)2 * N * 4);
  size_t o_offs = take((size_t)(N + 1) * 4);
  size_t o_eid  = take((size_t)E * 4);
  size_t o_qd   = take((size_t)N * 4);
  size_t o_qs   = take((size_t)N * 4);
  size_t o_qr   = take((size_t)NR * 4);
  size_t o_Pr   = take((size_t)NR * 128 * 2);
  size_t o_Wc   = take((size_t)256 * KMAX * 2);   // combined bf16 B [256][K]
  size_t o_Pd   = take((size_t)N * 128 * 2);
  size_t o_Ps   = take((size_t)N * 128 * 2);
  size_t need   = off;   // ~6.9 MB (proven resident)

  if (ws_size < need) {
    hipMemsetAsync(d_out, 0, (size_t)out_size * 4, stream);  // finite diagnostic
    return;
  }

  char* w = (char*)d_ws;
  int* counts = (int*)(w + o_cnt);
  int* cursor = counts + N;
  int* offs   = (int*)(w + o_offs);
  int* eid    = (int*)(w + o_eid);
  float* qd   = (float*)(w + o_qd);
  float* qs   = (float*)(w + o_qs);
  float* qr   = (float*)(w + o_qr);
  u16* Pr     = (u16*)(w + o_Pr);
  u16* Wc     = (u16*)(w + o_Wc);
  u16* Pd     = (u16*)(w + o_Pd);
  u16* Ps     = (u16*)(w + o_Ps);

  const int* esrc = ei;
  const int* edst = ei + E;

  hipMemsetAsync(counts, 0, (size_t)2 * N * 4, stream);
  hipMemsetAsync(eid, 0, (size_t)E * 4, stream);

  int egrid = (E + 255) / 256;
  hist_k<<<egrid, 256, 0, stream>>>(edst, counts, E, N);
  scan_k<<<1, 1024, 0, stream>>>(counts, offs, N);
  scatter_k<<<egrid, 256, 0, stream>>>(edst, offs, cursor, eid, E, N);

  int gemmGrid = (N + 15) / 16;

  for (int m = 0; m < 3; ++m) {
    const float *W1, *b1, *w2, *Amod, *Wmod, *bmod;
    int K;
    if (m == 0)      { W1 = W1s; b1 = b1s; w2 = w2s; Amod = semb;    Wmod = nullptr; bmod = nullptr; K = DIM; }
    else if (m == 1) { W1 = W1v; b1 = b1v; w2 = w2v; Amod = visual;  Wmod = Wv;      bmod = bv;      K = VIS; }
    else             { W1 = W1t; b1 = b1t; w2 = w2t; Amod = textual; Wmod = Wt;      bmod = bt;      K = TXT; }

    if (m == 0) {
      copy_w1b<<<256, 128, 0, stream>>>(W1, Wc);
    } else {
      prep_wc2<<<dim3((K + 255) / 256, 256), 256, 0, stream>>>(W1, Wmod, K, Wc);
    }
    prep_pr_q<<<NR, 128, 0, stream>>>(relemb, W1, b1, bmod, w2, Pr, qr, NR);

    gemm3_mfma<<<gemmGrid, 256, 0, stream>>>(Amod, Wc, w2, Pd, Ps, qd, qs, N, K);

    aggregate_m<<<(N + 3) / 4, 256, 0, stream>>>(eid, offs, esrc, et,
                                                 qd, qs, qr, Pd, Ps, Pr,
                                                 alphaP, gammaP, m, (m == 0) ? 1 : 0,
                                                 outp, N, NR, E);
  }
}

// Round 9
// 363.375 us; speedup vs baseline: 1.2305x; 1.2287x over previous
//
#include <hip/hip_runtime.h>
#include <hip/hip_bf16.h>

typedef unsigned short u16;
typedef unsigned int u32;
typedef __bf16 bf16x8 __attribute__((ext_vector_type(8)));
typedef float f32x4 __attribute__((ext_vector_type(4)));

#define DIM 128

__device__ __forceinline__ float bf2f(u16 v) { return __uint_as_float(((u32)v) << 16); }
__device__ __forceinline__ u16 f2bf_rne(float x) {
  u32 u = __float_as_uint(x);
  return (u16)((u + 0x7fffu + ((u >> 16) & 1u)) >> 16);
}
__device__ __forceinline__ float lrelu(float x) { return x > 0.f ? x : 0.01f * x; }
__device__ __forceinline__ int iclamp(int v, int hi) { return v < 0 ? 0 : (v >= hi ? hi - 1 : v); }
__device__ __forceinline__ float sane(float x) { return (x == x) ? x : 0.f; }

__device__ __forceinline__ float wred_max(float v) {
  #pragma unroll
  for (int o = 32; o > 0; o >>= 1) v = fmaxf(v, __shfl_xor(v, o, 64));
  return v;
}
__device__ __forceinline__ float wred_sum(float v) {
  #pragma unroll
  for (int o = 32; o > 0; o >>= 1) v += __shfl_xor(v, o, 64);
  return v;
}

// ---------------- CSR build ----------------
__global__ void hist_k(const int* __restrict__ dst, int* __restrict__ cnt, int E, int N) {
  int e = blockIdx.x * blockDim.x + threadIdx.x;
  if (e < E) {
    int d = dst[e];
    if (d >= 0 && d < N) atomicAdd(&cnt[d], 1);
  }
}

__global__ __launch_bounds__(1024) void scan_k(const int* __restrict__ cnt,
                                               int* __restrict__ offs, int N) {
  __shared__ int sums[1024];
  int t = threadIdx.x;
  int chunk = (N + 1023) >> 10;
  int base = t * chunk;
  int s = 0;
  for (int i = 0; i < chunk; ++i) { int idx = base + i; if (idx < N) s += cnt[idx]; }
  sums[t] = s;
  __syncthreads();
  for (int off = 1; off < 1024; off <<= 1) {
    int v = (t >= off) ? sums[t - off] : 0;
    __syncthreads();
    sums[t] += v;
    __syncthreads();
  }
  int prefix = (t > 0) ? sums[t - 1] : 0;
  for (int i = 0; i < chunk; ++i) {
    int idx = base + i;
    if (idx < N) { offs[idx] = prefix; prefix += cnt[idx]; }
  }
  if (t == 1023) offs[N] = sums[1023];
}

__global__ void scatter_k(const int* __restrict__ dst, const int* __restrict__ offs,
                          int* __restrict__ cursor, int* __restrict__ eid, int E, int N) {
  int e = blockIdx.x * blockDim.x + threadIdx.x;
  if (e < E) {
    int d = dst[e];
    if (d >= 0 && d < N) {
      int pos = offs[d] + atomicAdd(&cursor[d], 1);
      if (pos >= 0 && pos < E) eid[pos] = e;
    }
  }
}

// ================= FUSED PATH structs =================
struct PrepArgs {
  const float* W1[3]; const float* Wmod[3]; int K[3];
  u16* Wc[3];
};
struct PrArgs {
  const float* rel; const float* W1[3]; const float* b1[3];
  const float* bmod[3]; const float* w2[3];
  u16* Pr[3]; float* qr[3]; int NR;
};
struct GArgs {
  const float* A[3]; const u16* B[3]; const float* w2[3];
  u16* Pd[3]; u16* Ps[3]; float* qd[3]; float* qs[3];
  int M; int K[3];
};
struct AgArgs {
  const int* eid; const int* offs; const int* src; const int* etyp;
  const float* qd[3]; const float* qs[3]; const float* qr[3];
  const u16* Pd[3]; const u16* Ps[3]; const u16* Pr[3];
  const float* alphaP; const float* gammaP;
  float* outp; int N; int NR; int E;
};

// combined bf16 B[256][K] per modality; m=0 is a plain W1 split copy
__global__ void prep_wc_all(PrepArgs a) {
  int m = blockIdx.z;
  int K = a.K[m];
  int k = blockIdx.x * blockDim.x + threadIdx.x;
  int o = blockIdx.y;                       // 0..255
  if (k >= K) return;
  int half = (o >= 128) ? 128 : 0;
  int oo = o & 127;
  const float* W1 = a.W1[m];
  float acc;
  if (m == 0) {
    acc = W1[oo * 384 + half + k];
  } else {
    const float* Wm = a.Wmod[m];
    acc = 0.f;
    for (int i = 0; i < 128; ++i)
      acc += W1[oo * 384 + half + i] * Wm[i * K + k];
  }
  a.Wc[m][(size_t)o * K + k] = f2bf_rne(acc);
}

// Pr[m][r][o] (bf16) + qr[m][r] (f32); grid (NR,1,3), 128 threads
__global__ __launch_bounds__(128) void prep_pr_all(PrArgs a) {
  __shared__ float red[128];
  int m = blockIdx.z;
  int r = blockIdx.x;
  if (r >= a.NR) return;
  int o = threadIdx.x;
  const float* W1 = a.W1[m];
  float acc = a.b1[m][o];
  for (int i = 0; i < 128; ++i)
    acc += W1[o * 384 + 256 + i] * a.rel[r * 128 + i];
  const float* bmod = a.bmod[m];
  if (bmod != nullptr) {
    for (int i = 0; i < 128; ++i)
      acc += (W1[o * 384 + i] + W1[o * 384 + 128 + i]) * bmod[i];
  }
  a.Pr[m][(size_t)r * 128 + o] = f2bf_rne(acc);
  red[o] = acc * a.w2[m][o];
  __syncthreads();
  for (int s = 64; s > 0; s >>= 1) {
    if (o < s) red[o] += red[o + s];
    __syncthreads();
  }
  if (o == 0) a.qr[m][r] = sane(red[0]);
}

// barrier-free MFMA GEMM, all 3 modalities in one dispatch: grid (M/16, 3)
// wave wv: rows row0..+16, cols wv*64..+64; register double-buffered K-loop.
// C/D layout (verified): col = lane&15, row = (lane>>4)*4 + reg
__global__ __launch_bounds__(256) void gemm_all(GArgs g) {
  __shared__ float qpart[4][16];
  int m = blockIdx.y;
  const float* A = g.A[m];
  const u16* Bbf = g.B[m];
  const float* w2 = g.w2[m];
  int M = g.M, K = g.K[m];
  int tid = threadIdx.x;
  int lane = tid & 63, wv = tid >> 6;
  int quad = lane >> 4, l16 = lane & 15;
  int row0 = blockIdx.x * 16;

  int arow = row0 + l16;
  if (arow >= M) arow = M - 1;
  const float* Ap = A + (size_t)arow * K + quad * 8;
  const u16* Bp0 = Bbf + (size_t)(wv * 64 + 0  + l16) * K + quad * 8;
  const u16* Bp1 = Bbf + (size_t)(wv * 64 + 16 + l16) * K + quad * 8;
  const u16* Bp2 = Bbf + (size_t)(wv * 64 + 32 + l16) * K + quad * 8;
  const u16* Bp3 = Bbf + (size_t)(wv * 64 + 48 + l16) * K + quad * 8;

  f32x4 acc[4];
  #pragma unroll
  for (int t = 0; t < 4; ++t) acc[t] = (f32x4){0.f, 0.f, 0.f, 0.f};

  union AF { bf16x8 v; u32 w[4]; };

  // prologue loads (k=0)
  float4 ca0 = *reinterpret_cast<const float4*>(Ap);
  float4 ca1 = *reinterpret_cast<const float4*>(Ap + 4);
  bf16x8 cb0 = *reinterpret_cast<const bf16x8*>(Bp0);
  bf16x8 cb1 = *reinterpret_cast<const bf16x8*>(Bp1);
  bf16x8 cb2 = *reinterpret_cast<const bf16x8*>(Bp2);
  bf16x8 cb3 = *reinterpret_cast<const bf16x8*>(Bp3);

  for (int k0 = 0; k0 < K; k0 += 32) {
    int kn = (k0 + 32 < K) ? (k0 + 32) : k0;   // clamped: last trip reloads same (unused)
    float4 na0 = *reinterpret_cast<const float4*>(Ap + kn);
    float4 na1 = *reinterpret_cast<const float4*>(Ap + kn + 4);
    bf16x8 nb0 = *reinterpret_cast<const bf16x8*>(Bp0 + kn);
    bf16x8 nb1 = *reinterpret_cast<const bf16x8*>(Bp1 + kn);
    bf16x8 nb2 = *reinterpret_cast<const bf16x8*>(Bp2 + kn);
    bf16x8 nb3 = *reinterpret_cast<const bf16x8*>(Bp3 + kn);

    AF af;
    af.w[0] = (u32)f2bf_rne(ca0.x) | ((u32)f2bf_rne(ca0.y) << 16);
    af.w[1] = (u32)f2bf_rne(ca0.z) | ((u32)f2bf_rne(ca0.w) << 16);
    af.w[2] = (u32)f2bf_rne(ca1.x) | ((u32)f2bf_rne(ca1.y) << 16);
    af.w[3] = (u32)f2bf_rne(ca1.z) | ((u32)f2bf_rne(ca1.w) << 16);
    acc[0] = __builtin_amdgcn_mfma_f32_16x16x32_bf16(af.v, cb0, acc[0], 0, 0, 0);
    acc[1] = __builtin_amdgcn_mfma_f32_16x16x32_bf16(af.v, cb1, acc[1], 0, 0, 0);
    acc[2] = __builtin_amdgcn_mfma_f32_16x16x32_bf16(af.v, cb2, acc[2], 0, 0, 0);
    acc[3] = __builtin_amdgcn_mfma_f32_16x16x32_bf16(af.v, cb3, acc[3], 0, 0, 0);

    ca0 = na0; ca1 = na1;
    cb0 = nb0; cb1 = nb1; cb2 = nb2; cb3 = nb3;
  }

  u16* Pd = g.Pd[m];
  u16* Ps = g.Ps[m];
  float w2c[4];
  #pragma unroll
  for (int t = 0; t < 4; ++t) w2c[t] = w2[(wv & 1) * 64 + t * 16 + l16];

  float part[4];
  #pragma unroll
  for (int r = 0; r < 4; ++r) {
    int rr = row0 + quad * 4 + r;
    bool ok = rr < M;
    float qp = 0.f;
    #pragma unroll
    for (int t = 0; t < 4; ++t) {
      int c = (wv & 1) * 64 + t * 16 + l16;
      if (ok) {
        if (wv < 2) Pd[(size_t)rr * 128 + c] = f2bf_rne(acc[t][r]);
        else        Ps[(size_t)rr * 128 + c] = f2bf_rne(acc[t][r]);
      }
      qp += acc[t][r] * w2c[t];
    }
    #pragma unroll
    for (int mk = 1; mk < 16; mk <<= 1) qp += __shfl_xor(qp, mk, 64);
    part[r] = qp;
  }
  if (l16 == 0) {
    #pragma unroll
    for (int r = 0; r < 4; ++r) qpart[wv][quad * 4 + r] = part[r];
  }
  __syncthreads();
  if (tid < 32) {
    int row = tid & 15;
    int rr = row0 + row;
    if (rr < M) {
      if (tid < 16) g.qd[m][rr] = sane(qpart[0][row] + qpart[1][row]);
      else          g.qs[m][rr] = sane(qpart[2][row] + qpart[3][row]);
    }
  }
}

// fused 3-modality softmax+aggregate; one wave per node; direct final store
__global__ __launch_bounds__(256) void aggregate_all(AgArgs a) {
  int n = blockIdx.x * 4 + (threadIdx.x >> 6);
  if (n >= a.N) return;
  int lane = threadIdx.x & 63;
  int N = a.N, NR = a.NR, E = a.E;
  int eb = a.offs[n], ee = a.offs[n + 1];
  if (eb < 0) eb = 0;
  if (eb > E) eb = E;
  if (ee < eb) ee = eb;
  if (ee > E) ee = E;
  int En = ee - eb;

  float al = a.alphaP[0];
  if (!(al > 0.f && al < 1.f)) al = 0.1f;
  float ga = a.gammaP[0];
  if (!(ga > 0.f && ga < 1.f)) ga = 0.8f;
  float coef[3] = {1.f - al - ga, al, ga};

  float qdn[3];
  #pragma unroll
  for (int m = 0; m < 3; ++m) qdn[m] = sane(a.qd[m][n]);

  // pass 1: segment max per modality (edge indices read once)
  float mx[3] = {-1e30f, -1e30f, -1e30f};
  for (int i = lane; i < En; i += 64) {
    int e = iclamp(a.eid[eb + i], E);
    int s = iclamp(a.src[e], N);
    int t = iclamp(a.etyp[e], NR);
    #pragma unroll
    for (int m = 0; m < 3; ++m)
      mx[m] = fmaxf(mx[m], lrelu(qdn[m] + sane(a.qs[m][s]) + sane(a.qr[m][t])));
  }
  #pragma unroll
  for (int m = 0; m < 3; ++m) mx[m] = wred_max(mx[m]);

  // pass 2: z + unnormalized accumulation, chunk-outer / modality-inner
  float z[3] = {0.f, 0.f, 0.f};
  float a0[3] = {0.f, 0.f, 0.f};
  float a1[3] = {0.f, 0.f, 0.f};
  for (int c0 = 0; c0 < En; c0 += 64) {
    int cn = min(64, En - c0);
    float wr[3] = {0.f, 0.f, 0.f};
    int s = 0, t = 0;
    if (lane < cn) {
      int e = iclamp(a.eid[eb + c0 + lane], E);
      s = iclamp(a.src[e], N);
      t = iclamp(a.etyp[e], NR);
      #pragma unroll
      for (int m = 0; m < 3; ++m) {
        float b = lrelu(qdn[m] + sane(a.qs[m][s]) + sane(a.qr[m][t]));
        float arg = fmaxf(fminf(b - mx[m], 0.f), -80.f);
        wr[m] = __expf(arg);
      }
    }
    #pragma unroll
    for (int m = 0; m < 3; ++m) z[m] += wr[m];
    for (int j = 0; j < cn; ++j) {
      int sj = __shfl(s, j, 64);
      int tj = __shfl(t, j, 64);
      float w0 = __shfl(wr[0], j, 64);
      float w1 = __shfl(wr[1], j, 64);
      float w2 = __shfl(wr[2], j, 64);
      float wj[3] = {w0, w1, w2};
      #pragma unroll
      for (int m = 0; m < 3; ++m) {
        u32 pu = *reinterpret_cast<const u32*>(a.Ps[m] + (size_t)sj * 128 + 2 * lane);
        u32 ru = *reinterpret_cast<const u32*>(a.Pr[m] + (size_t)tj * 128 + 2 * lane);
        float ps0 = __uint_as_float(pu << 16), ps1 = __uint_as_float(pu & 0xffff0000u);
        float pr0 = __uint_as_float(ru << 16), pr1 = __uint_as_float(ru & 0xffff0000u);
        a0[m] = fmaf(wj[m], sane(ps0) + sane(pr0), a0[m]);
        a1[m] = fmaf(wj[m], sane(ps1) + sane(pr1), a1[m]);
      }
    }
  }
  #pragma unroll
  for (int m = 0; m < 3; ++m) z[m] = wred_sum(z[m]);

  float o0 = 0.f, o1 = 0.f;
  #pragma unroll
  for (int m = 0; m < 3; ++m) {
    float h0 = 0.f, h1 = 0.f;
    if (En > 0 && z[m] > 0.f) {
      float rz = 1.f / z[m];
      u32 du = *reinterpret_cast<const u32*>(a.Pd[m] + (size_t)n * 128 + 2 * lane);
      float pd0 = __uint_as_float(du << 16), pd1 = __uint_as_float(du & 0xffff0000u);
      h0 = lrelu(sane(pd0) + a0[m] * rz);
      h1 = lrelu(sane(pd1) + a1[m] * rz);
    }
    o0 = fmaf(coef[m], h0, o0);
    o1 = fmaf(coef[m], h1, o1);
  }
  float* op = a.outp + (size_t)n * 128 + 2 * lane;
  op[0] = sane(o0);
  op[1] = sane(o1);
}

// ================= SERIAL FALLBACK kernels (round-8, proven) =================
__global__ void prep_wc2(const float* __restrict__ W1, const float* __restrict__ Wmod,
                         int K, u16* __restrict__ out) {
  int k = blockIdx.x * blockDim.x + threadIdx.x;
  int o = blockIdx.y;
  if (k >= K) return;
  int half = (o >= 128) ? 128 : 0;
  int oo = o & 127;
  float acc = 0.f;
  for (int i = 0; i < 128; ++i)
    acc += W1[oo * 384 + half + i] * Wmod[i * K + k];
  out[(size_t)o * K + k] = f2bf_rne(acc);
}

__global__ void copy_w1b(const float* __restrict__ W1, u16* __restrict__ out) {
  int k = threadIdx.x;
  int o = blockIdx.x;
  int half = (o >= 128) ? 128 : 0;
  int oo = o & 127;
  out[o * 128 + k] = f2bf_rne(W1[oo * 384 + half + k]);
}

__global__ __launch_bounds__(128) void prep_pr_q(
    const float* __restrict__ rel, const float* __restrict__ W1,
    const float* __restrict__ b1, const float* __restrict__ bmod,
    const float* __restrict__ w2,
    u16* __restrict__ Pr, float* __restrict__ qr, int NR) {
  __shared__ float red[128];
  int r = blockIdx.x;
  if (r >= NR) return;
  int o = threadIdx.x;
  float acc = b1[o];
  for (int i = 0; i < 128; ++i)
    acc += W1[o * 384 + 256 + i] * rel[r * 128 + i];
  if (bmod != nullptr) {
    for (int i = 0; i < 128; ++i)
      acc += (W1[o * 384 + i] + W1[o * 384 + 128 + i]) * bmod[i];
  }
  Pr[(size_t)r * 128 + o] = f2bf_rne(acc);
  red[o] = acc * w2[o];
  __syncthreads();
  for (int s = 64; s > 0; s >>= 1) {
    if (o < s) red[o] += red[o + s];
    __syncthreads();
  }
  if (o == 0) qr[r] = sane(red[0]);
}

__global__ __launch_bounds__(256) void aggregate_m(
    const int* __restrict__ eid, const int* __restrict__ offs,
    const int* __restrict__ src, const int* __restrict__ etyp,
    const float* __restrict__ qd, const float* __restrict__ qs, const float* __restrict__ qr,
    const u16* __restrict__ Pd, const u16* __restrict__ Ps, const u16* __restrict__ Pr,
    const float* __restrict__ alphaP, const float* __restrict__ gammaP,
    int mIdx, int first,
    float* __restrict__ outp,
    int N, int NR, int E) {
  int n = blockIdx.x * 4 + (threadIdx.x >> 6);
  if (n >= N) return;
  int lane = threadIdx.x & 63;
  int eb = offs[n], ee = offs[n + 1];
  if (eb < 0) eb = 0;
  if (eb > E) eb = E;
  if (ee < eb) ee = eb;
  if (ee > E) ee = E;
  int En = ee - eb;

  float al = alphaP[0];
  if (!(al > 0.f && al < 1.f)) al = 0.1f;
  float ga = gammaP[0];
  if (!(ga > 0.f && ga < 1.f)) ga = 0.8f;
  float coef = (mIdx == 0) ? (1.f - al - ga) : (mIdx == 1 ? al : ga);

  float qdn = sane(qd[n]);
  float mx = -1e30f;
  for (int i = lane; i < En; i += 64) {
    int e = iclamp(eid[eb + i], E);
    int s = iclamp(src[e], N);
    int t = iclamp(etyp[e], NR);
    mx = fmaxf(mx, lrelu(qdn + sane(qs[s]) + sane(qr[t])));
  }
  mx = wred_max(mx);

  float z = 0.f, a0 = 0.f, a1 = 0.f;
  for (int c0 = 0; c0 < En; c0 += 64) {
    int cn = min(64, En - c0);
    float wraw = 0.f;
    int s = 0, t = 0;
    if (lane < cn) {
      int e = iclamp(eid[eb + c0 + lane], E);
      s = iclamp(src[e], N);
      t = iclamp(etyp[e], NR);
      float b = lrelu(qdn + sane(qs[s]) + sane(qr[t]));
      float arg = fmaxf(fminf(b - mx, 0.f), -80.f);
      wraw = __expf(arg);
    }
    z += wraw;
    for (int j = 0; j < cn; ++j) {
      float wj = __shfl(wraw, j, 64);
      int sj = __shfl(s, j, 64);
      int tj = __shfl(t, j, 64);
      u32 pu = *reinterpret_cast<const u32*>(Ps + (size_t)sj * 128 + 2 * lane);
      u32 ru = *reinterpret_cast<const u32*>(Pr + (size_t)tj * 128 + 2 * lane);
      float ps0 = __uint_as_float(pu << 16), ps1 = __uint_as_float(pu & 0xffff0000u);
      float pr0 = __uint_as_float(ru << 16), pr1 = __uint_as_float(ru & 0xffff0000u);
      a0 = fmaf(wj, sane(ps0) + sane(pr0), a0);
      a1 = fmaf(wj, sane(ps1) + sane(pr1), a1);
    }
  }
  z = wred_sum(z);

  float h0 = 0.f, h1 = 0.f;
  if (En > 0 && z > 0.f) {
    float rz = 1.f / z;
    u32 du = *reinterpret_cast<const u32*>(Pd + (size_t)n * 128 + 2 * lane);
    float pd0 = __uint_as_float(du << 16), pd1 = __uint_as_float(du & 0xffff0000u);
    h0 = lrelu(sane(pd0) + a0 * rz);
    h1 = lrelu(sane(pd1) + a1 * rz);
  }
  float c0v = sane(coef * h0);
  float c1v = sane(coef * h1);

  float* op = outp + (size_t)n * 128 + 2 * lane;
  if (first) { op[0] = c0v; op[1] = c1v; }
  else       { op[0] = sane(op[0]) + c0v; op[1] = sane(op[1]) + c1v; }
}

extern "C" void kernel_launch(void* const* d_in, const int* in_sizes, int n_in,
                              void* d_out, int out_size, void* d_ws, size_t ws_size,
                              hipStream_t stream) {
  const int* ei        = (const int*)d_in[1];
  const int* et        = (const int*)d_in[2];
  const float* visual  = (const float*)d_in[3];
  const float* textual = (const float*)d_in[4];
  const float* semb    = (const float*)d_in[5];
  const float* relemb  = (const float*)d_in[6];
  const float* W1s = (const float*)d_in[7];
  const float* b1s = (const float*)d_in[8];
  const float* w2s = (const float*)d_in[9];
  const float* W1v = (const float*)d_in[10];
  const float* b1v = (const float*)d_in[11];
  const float* w2v = (const float*)d_in[12];
  const float* W1t = (const float*)d_in[13];
  const float* b1t = (const float*)d_in[14];
  const float* w2t = (const float*)d_in[15];
  const float* Wv  = (const float*)d_in[16];
  const float* bv  = (const float*)d_in[17];
  const float* Wt  = (const float*)d_in[18];
  const float* bt  = (const float*)d_in[19];
  const float* alphaP = (const float*)d_in[20];
  const float* gammaP = (const float*)d_in[21];
  float* outp = (float*)d_out;

  const int E   = in_sizes[2];
  const int N   = in_sizes[5] / DIM;
  const int NR  = in_sizes[6] / DIM;
  const int VIS = in_sizes[3] / N;   // 512
  const int TXT = in_sizes[4] / N;   // 768
  const int KMAX = (TXT > VIS) ? TXT : VIS;
  int Ks[3] = {DIM, VIS, TXT};

  const float* W1a[3]   = {W1s, W1v, W1t};
  const float* b1a[3]   = {b1s, b1v, b1t};
  const float* w2a[3]   = {w2s, w2v, w2t};
  const float* Wmoda[3] = {nullptr, Wv, Wt};
  const float* bmoda[3] = {nullptr, bv, bt};
  const float* Amoda[3] = {semb, visual, textual};

  const int* esrc = ei;
  const int* edst = ei + E;
  int egrid = (E + 255) / 256;

  // ---- fused-path layout ----
  size_t off = 0;
  auto take = [&](size_t bytes) -> size_t {
    size_t o = off;
    off = (off + bytes + 255) & ~(size_t)255;
    return o;
  };
  size_t o_cnt  = take((size_t)2 * N * 4);
  size_t o_offs = take((size_t)(N + 1) * 4);
  size_t o_eid  = take((size_t)E * 4);
  size_t o_qdm[3], o_qsm[3], o_qrm[3], o_Prm[3], o_Wcm[3], o_Pdm[3], o_Psm[3];
  for (int m = 0; m < 3; ++m) {
    o_qdm[m] = take((size_t)N * 4);
    o_qsm[m] = take((size_t)N * 4);
    o_qrm[m] = take((size_t)NR * 4);
    o_Prm[m] = take((size_t)NR * 128 * 2);
    o_Wcm[m] = take((size_t)256 * Ks[m] * 2);
    o_Pdm[m] = take((size_t)N * 128 * 2);
    o_Psm[m] = take((size_t)N * 128 * 2);
  }
  size_t need_fused = off;   // ~18 MB

  // ---- serial-path layout (round-8, proven ~6.9 MB) ----
  off = 0;
  size_t s_cnt  = take((size_t)2 * N * 4);
  size_t s_offs = take((size_t)(N + 1) * 4);
  size_t s_eid  = take((size_t)E * 4);
  size_t s_qd   = take((size_t)N * 4);
  size_t s_qs   = take((size_t)N * 4);
  size_t s_qr   = take((size_t)NR * 4);
  size_t s_Pr   = take((size_t)NR * 128 * 2);
  size_t s_Wc   = take((size_t)256 * KMAX * 2);
  size_t s_Pd   = take((size_t)N * 128 * 2);
  size_t s_Ps   = take((size_t)N * 128 * 2);
  size_t need_serial = off;

  char* w = (char*)d_ws;

  if (ws_size >= need_fused) {
    // =========== FUSED PATH ===========
    int* counts = (int*)(w + o_cnt);
    int* cursor = counts + N;
    int* offs   = (int*)(w + o_offs);
    int* eid    = (int*)(w + o_eid);

    hipMemsetAsync(counts, 0, (size_t)2 * N * 4, stream);
    hipMemsetAsync(eid, 0, (size_t)E * 4, stream);
    hist_k<<<egrid, 256, 0, stream>>>(edst, counts, E, N);
    scan_k<<<1, 1024, 0, stream>>>(counts, offs, N);
    scatter_k<<<egrid, 256, 0, stream>>>(edst, offs, cursor, eid, E, N);

    PrepArgs pa;
    PrArgs ra;
    GArgs ga;
    AgArgs aa;
    ra.rel = relemb; ra.NR = NR;
    ga.M = N;
    for (int m = 0; m < 3; ++m) {
      pa.W1[m] = W1a[m]; pa.Wmod[m] = Wmoda[m]; pa.K[m] = Ks[m];
      pa.Wc[m] = (u16*)(w + o_Wcm[m]);
      ra.W1[m] = W1a[m]; ra.b1[m] = b1a[m]; ra.bmod[m] = bmoda[m]; ra.w2[m] = w2a[m];
      ra.Pr[m] = (u16*)(w + o_Prm[m]); ra.qr[m] = (float*)(w + o_qrm[m]);
      ga.A[m] = Amoda[m]; ga.B[m] = (const u16*)(w + o_Wcm[m]); ga.w2[m] = w2a[m];
      ga.Pd[m] = (u16*)(w + o_Pdm[m]); ga.Ps[m] = (u16*)(w + o_Psm[m]);
      ga.qd[m] = (float*)(w + o_qdm[m]); ga.qs[m] = (float*)(w + o_qsm[m]);
      ga.K[m] = Ks[m];
      aa.qd[m] = (const float*)(w + o_qdm[m]);
      aa.qs[m] = (const float*)(w + o_qsm[m]);
      aa.qr[m] = (const float*)(w + o_qrm[m]);
      aa.Pd[m] = (const u16*)(w + o_Pdm[m]);
      aa.Ps[m] = (const u16*)(w + o_Psm[m]);
      aa.Pr[m] = (const u16*)(w + o_Prm[m]);
    }
    aa.eid = eid; aa.offs = offs; aa.src = esrc; aa.etyp = et;
    aa.alphaP = alphaP; aa.gammaP = gammaP;
    aa.outp = outp; aa.N = N; aa.NR = NR; aa.E = E;

    prep_wc_all<<<dim3((KMAX + 255) / 256, 256, 3), 256, 0, stream>>>(pa);
    prep_pr_all<<<dim3(NR, 1, 3), 128, 0, stream>>>(ra);
    gemm_all<<<dim3((N + 15) / 16, 3), 256, 0, stream>>>(ga);
    aggregate_all<<<(N + 3) / 4, 256, 0, stream>>>(aa);
    return;
  }

  if (ws_size < need_serial) {
    hipMemsetAsync(d_out, 0, (size_t)out_size * 4, stream);  // finite diagnostic
    return;
  }

  // =========== SERIAL FALLBACK (round-8 behavior) ===========
  int* counts = (int*)(w + s_cnt);
  int* cursor = counts + N;
  int* offs   = (int*)(w + s_offs);
  int* eid    = (int*)(w + s_eid);
  float* qd   = (float*)(w + s_qd);
  float* qs   = (float*)(w + s_qs);
  float* qr   = (float*)(w + s_qr);
  u16* Pr     = (u16*)(w + s_Pr);
  u16* Wc     = (u16*)(w + s_Wc);
  u16* Pd     = (u16*)(w + s_Pd);
  u16* Ps     = (u16*)(w + s_Ps);

  hipMemsetAsync(counts, 0, (size_t)2 * N * 4, stream);
  hipMemsetAsync(eid, 0, (size_t)E * 4, stream);
  hist_k<<<egrid, 256, 0, stream>>>(edst, counts, E, N);
  scan_k<<<1, 1024, 0, stream>>>(counts, offs, N);
  scatter_k<<<egrid, 256, 0, stream>>>(edst, offs, cursor, eid, E, N);

  for (int m = 0; m < 3; ++m) {
    if (m == 0) {
      copy_w1b<<<256, 128, 0, stream>>>(W1a[m], Wc);
    } else {
      prep_wc2<<<dim3((Ks[m] + 255) / 256, 256), 256, 0, stream>>>(W1a[m], Wmoda[m], Ks[m], Wc);
    }
    prep_pr_q<<<NR, 128, 0, stream>>>(relemb, W1a[m], b1a[m], bmoda[m], w2a[m], Pr, qr, NR);

    GArgs ga;
    ga.A[0] = Amoda[m]; ga.B[0] = Wc; ga.w2[0] = w2a[m];
    ga.Pd[0] = Pd; ga.Ps[0] = Ps; ga.qd[0] = qd; ga.qs[0] = qs;
    ga.M = N; ga.K[0] = Ks[m];
    gemm_all<<<dim3((N + 15) / 16, 1), 256, 0, stream>>>(ga);

    aggregate_m<<<(N + 3) / 4, 256, 0, stream>>>(eid, offs, esrc, et,
                                                 qd, qs, qr, Pd, Ps, Pr,
                                                 alphaP, gammaP, m, (m == 0) ? 1 : 0,
                                                 outp, N, NR, E);
  }
}

// Round 10
// 330.869 us; speedup vs baseline: 1.3514x; 1.0982x over previous
//
#include <hip/hip_runtime.h>
#include <hip/hip_bf16.h>

typedef unsigned short u16;
typedef unsigned int u32;
typedef __bf16 bf16x8 __attribute__((ext_vector_type(8)));
typedef float f32x4 __attribute__((ext_vector_type(4)));

#define DIM 128

__device__ __forceinline__ float bf2f(u16 v) { return __uint_as_float(((u32)v) << 16); }
__device__ __forceinline__ u16 f2bf_rne(float x) {
  u32 u = __float_as_uint(x);
  return (u16)((u + 0x7fffu + ((u >> 16) & 1u)) >> 16);
}
__device__ __forceinline__ float lrelu(float x) { return x > 0.f ? x : 0.01f * x; }
__device__ __forceinline__ int iclamp(int v, int hi) { return v < 0 ? 0 : (v >= hi ? hi - 1 : v); }
__device__ __forceinline__ float sane(float x) { return (x == x) ? x : 0.f; }

__device__ __forceinline__ float wred_max(float v) {
  #pragma unroll
  for (int o = 32; o > 0; o >>= 1) v = fmaxf(v, __shfl_xor(v, o, 64));
  return v;
}
__device__ __forceinline__ float wred_sum(float v) {
  #pragma unroll
  for (int o = 32; o > 0; o >>= 1) v += __shfl_xor(v, o, 64);
  return v;
}

// ---------------- CSR build ----------------
__global__ void hist_k(const int* __restrict__ dst, int* __restrict__ cnt, int E, int N) {
  int e = blockIdx.x * blockDim.x + threadIdx.x;
  if (e < E) {
    int d = dst[e];
    if (d >= 0 && d < N) atomicAdd(&cnt[d], 1);
  }
}

__global__ __launch_bounds__(1024) void scan_k(const int* __restrict__ cnt,
                                               int* __restrict__ offs, int N) {
  __shared__ int sums[1024];
  int t = threadIdx.x;
  int chunk = (N + 1023) >> 10;
  int base = t * chunk;
  int s = 0;
  for (int i = 0; i < chunk; ++i) { int idx = base + i; if (idx < N) s += cnt[idx]; }
  sums[t] = s;
  __syncthreads();
  for (int off = 1; off < 1024; off <<= 1) {
    int v = (t >= off) ? sums[t - off] : 0;
    __syncthreads();
    sums[t] += v;
    __syncthreads();
  }
  int prefix = (t > 0) ? sums[t - 1] : 0;
  for (int i = 0; i < chunk; ++i) {
    int idx = base + i;
    if (idx < N) { offs[idx] = prefix; prefix += cnt[idx]; }
  }
  if (t == 1023) offs[N] = sums[1023];
}

__global__ void scatter_k(const int* __restrict__ dst, const int* __restrict__ offs,
                          int* __restrict__ cursor, int* __restrict__ eid, int E, int N) {
  int e = blockIdx.x * blockDim.x + threadIdx.x;
  if (e < E) {
    int d = dst[e];
    if (d >= 0 && d < N) {
      int pos = offs[d] + atomicAdd(&cursor[d], 1);
      if (pos >= 0 && pos < E) eid[pos] = e;
    }
  }
}

// ================= structs =================
struct PrepArgs {
  const float* W1[3]; const float* Wmod[3]; int K[3]; int isCopy[3];
  u16* Wc[3];
};
struct PrArgs {
  const float* rel; const float* W1[3]; const float* b1[3];
  const float* bmod[3]; const float* w2[3];
  u16* Pr[3]; float* qr[3]; int NR;
};
struct CArgs { const float* A[3]; u16* Ap[3]; int K[3]; int M; };
struct GArgs {
  const float* A[3]; const u16* B[3]; const float* w2[3];
  u16* Pd[3]; u16* Ps[3]; float* qd[3]; float* qs[3];
  int M; int K[3];
};
struct GpArgs {
  const u16* Ap[3]; const u16* B[3]; const float* w2[3];
  u16* Pd[3]; u16* Ps[3]; float* qd[3]; float* qs[3];
  int M; int K[3];
};
struct AgArgs {
  const int* eid; const int* offs; const int* src; const int* etyp;
  const float* qd[3]; const float* qs[3]; const float* qr[3];
  const u16* Pd[3]; const u16* Ps[3]; const u16* Pr[3];
  const float* alphaP; const float* gammaP;
  float* outp; int N; int NR; int E;
};

// combined bf16 B, PACKED trip-major: Wc[((k>>5)*256 + o)*32 + (k&31)]
__global__ void prep_wc_all(PrepArgs a) {
  int m = blockIdx.z;
  int K = a.K[m];
  int k = blockIdx.x * blockDim.x + threadIdx.x;
  int o = blockIdx.y;                       // 0..255
  if (k >= K) return;
  int half = (o >= 128) ? 128 : 0;
  int oo = o & 127;
  const float* W1 = a.W1[m];
  float acc;
  if (a.isCopy[m]) {
    acc = W1[oo * 384 + half + k];
  } else {
    const float* Wm = a.Wmod[m];
    acc = 0.f;
    for (int i = 0; i < 128; ++i)
      acc += W1[oo * 384 + half + i] * Wm[i * K + k];
  }
  a.Wc[m][((size_t)(k >> 5) * 256 + o) * 32 + (k & 31)] = f2bf_rne(acc);
}

// Pr[m][r][o] (bf16) + qr[m][r] (f32); grid (NR,1,3), 128 threads
__global__ __launch_bounds__(128) void prep_pr_all(PrArgs a) {
  __shared__ float red[128];
  int m = blockIdx.z;
  int r = blockIdx.x;
  if (r >= a.NR) return;
  int o = threadIdx.x;
  const float* W1 = a.W1[m];
  float acc = a.b1[m][o];
  for (int i = 0; i < 128; ++i)
    acc += W1[o * 384 + 256 + i] * a.rel[r * 128 + i];
  const float* bmod = a.bmod[m];
  if (bmod != nullptr) {
    for (int i = 0; i < 128; ++i)
      acc += (W1[o * 384 + i] + W1[o * 384 + 128 + i]) * bmod[i];
  }
  a.Pr[m][(size_t)r * 128 + o] = f2bf_rne(acc);
  red[o] = acc * a.w2[m][o];
  __syncthreads();
  for (int s = 64; s > 0; s >>= 1) {
    if (o < s) red[o] += red[o + s];
    __syncthreads();
  }
  if (o == 0) a.qr[m][r] = sane(red[0]);
}

// A f32 → bf16, PACKED trip-major per 16-row group:
// Ap[((g*nt + kb)*16 + row)*32 + c]   (grid: (ceil(M/16), 3), 256 thr)
__global__ __launch_bounds__(256) void convertA(CArgs a) {
  int m = blockIdx.y;
  int K = a.K[m];
  int nt = K >> 5;
  int g = blockIdx.x;
  int t = threadIdx.x;
  int row = t >> 4;
  int cp = (t & 15) * 2;
  int gr = g * 16 + row;
  bool valid = gr < a.M;
  const float* src = a.A[m] + (size_t)(valid ? gr : 0) * K;
  u16* dst = a.Ap[m] + (size_t)g * nt * 512;
  for (int kb = 0; kb < nt; ++kb) {
    float2 v = make_float2(0.f, 0.f);
    if (valid) v = *reinterpret_cast<const float2*>(src + kb * 32 + cp);
    *reinterpret_cast<u32*>(dst + (kb * 16 + row) * 32 + cp) =
        (u32)f2bf_rne(v.x) | ((u32)f2bf_rne(v.y) << 16);
  }
}

// ---------- packed-A + packed-B barrier-free MFMA GEMM (P1) ----------
// grid (M/16, 3), 256 thr; wave wv: 16 rows × cols wv*64..+64.
// All loads are contiguous 1-KB wave transactions. A prefetched 4 trips ahead.
// C/D layout (verified): col = lane&15, row = (lane>>4)*4 + reg
__global__ __launch_bounds__(256) void gemm_pk(GpArgs g) {
  __shared__ float qpart[4][16];
  int m = blockIdx.y;
  const u16* Apk = g.Ap[m];
  const u16* Bpk = g.B[m];
  const float* w2 = g.w2[m];
  int M = g.M, K = g.K[m];
  int nt = K >> 5;                          // 4, 16, or 24 (all ≥4, even)
  int tid = threadIdx.x;
  int lane = tid & 63, wv = tid >> 6;
  int quad = lane >> 4, l16 = lane & 15;
  int row0 = blockIdx.x * 16;

  const u16* Apg = Apk + (size_t)blockIdx.x * nt * 512 + l16 * 32 + quad * 8;
  const u16* Bpg = Bpk + (size_t)(wv * 64 + l16) * 32 + quad * 8;

  f32x4 acc[4];
  #pragma unroll
  for (int t = 0; t < 4; ++t) acc[t] = (f32x4){0.f, 0.f, 0.f, 0.f};

  bf16x8 a0 = *reinterpret_cast<const bf16x8*>(Apg);
  bf16x8 a1 = *reinterpret_cast<const bf16x8*>(Apg + 512);
  bf16x8 a2 = *reinterpret_cast<const bf16x8*>(Apg + 1024);
  bf16x8 a3 = *reinterpret_cast<const bf16x8*>(Apg + 1536);

  for (int kb = 0; kb < nt; kb += 2) {
    int kp0 = kb + 4; if (kp0 >= nt) kp0 = kb;
    int kp1 = kb + 5; if (kp1 >= nt) kp1 = kb;
    bf16x8 na0 = *reinterpret_cast<const bf16x8*>(Apg + (size_t)kp0 * 512);
    bf16x8 na1 = *reinterpret_cast<const bf16x8*>(Apg + (size_t)kp1 * 512);

    const u16* b0p = Bpg + (size_t)kb * 8192;
    bf16x8 b00 = *reinterpret_cast<const bf16x8*>(b0p);
    bf16x8 b01 = *reinterpret_cast<const bf16x8*>(b0p + 512);
    bf16x8 b02 = *reinterpret_cast<const bf16x8*>(b0p + 1024);
    bf16x8 b03 = *reinterpret_cast<const bf16x8*>(b0p + 1536);
    const u16* b1p = b0p + 8192;
    bf16x8 b10 = *reinterpret_cast<const bf16x8*>(b1p);
    bf16x8 b11 = *reinterpret_cast<const bf16x8*>(b1p + 512);
    bf16x8 b12 = *reinterpret_cast<const bf16x8*>(b1p + 1024);
    bf16x8 b13 = *reinterpret_cast<const bf16x8*>(b1p + 1536);

    acc[0] = __builtin_amdgcn_mfma_f32_16x16x32_bf16(a0, b00, acc[0], 0, 0, 0);
    acc[1] = __builtin_amdgcn_mfma_f32_16x16x32_bf16(a0, b01, acc[1], 0, 0, 0);
    acc[2] = __builtin_amdgcn_mfma_f32_16x16x32_bf16(a0, b02, acc[2], 0, 0, 0);
    acc[3] = __builtin_amdgcn_mfma_f32_16x16x32_bf16(a0, b03, acc[3], 0, 0, 0);
    acc[0] = __builtin_amdgcn_mfma_f32_16x16x32_bf16(a1, b10, acc[0], 0, 0, 0);
    acc[1] = __builtin_amdgcn_mfma_f32_16x16x32_bf16(a1, b11, acc[1], 0, 0, 0);
    acc[2] = __builtin_amdgcn_mfma_f32_16x16x32_bf16(a1, b12, acc[2], 0, 0, 0);
    acc[3] = __builtin_amdgcn_mfma_f32_16x16x32_bf16(a1, b13, acc[3], 0, 0, 0);

    a0 = a2; a1 = a3; a2 = na0; a3 = na1;
  }

  u16* Pd = g.Pd[m];
  u16* Ps = g.Ps[m];
  float w2c[4];
  #pragma unroll
  for (int t = 0; t < 4; ++t) w2c[t] = w2[(wv & 1) * 64 + t * 16 + l16];

  float part[4];
  #pragma unroll
  for (int r = 0; r < 4; ++r) {
    int rr = row0 + quad * 4 + r;
    bool ok = rr < M;
    float qp = 0.f;
    #pragma unroll
    for (int t = 0; t < 4; ++t) {
      int c = (wv & 1) * 64 + t * 16 + l16;
      if (ok) {
        if (wv < 2) Pd[(size_t)rr * 128 + c] = f2bf_rne(acc[t][r]);
        else        Ps[(size_t)rr * 128 + c] = f2bf_rne(acc[t][r]);
      }
      qp += acc[t][r] * w2c[t];
    }
    #pragma unroll
    for (int mk = 1; mk < 16; mk <<= 1) qp += __shfl_xor(qp, mk, 64);
    part[r] = qp;
  }
  if (l16 == 0) {
    #pragma unroll
    for (int r = 0; r < 4; ++r) qpart[wv][quad * 4 + r] = part[r];
  }
  __syncthreads();
  if (tid < 32) {
    int row = tid & 15;
    int rr = row0 + row;
    if (rr < M) {
      if (tid < 16) g.qd[m][rr] = sane(qpart[0][row] + qpart[1][row]);
      else          g.qs[m][rr] = sane(qpart[2][row] + qpart[3][row]);
    }
  }
}

// ---------- f32-A GEMM (P2/P3 fallback; R9 body, packed-B addressing) ----------
__global__ __launch_bounds__(256) void gemm_all(GArgs g) {
  __shared__ float qpart[4][16];
  int m = blockIdx.y;
  const float* A = g.A[m];
  const u16* Bpk = g.B[m];
  const float* w2 = g.w2[m];
  int M = g.M, K = g.K[m];
  int tid = threadIdx.x;
  int lane = tid & 63, wv = tid >> 6;
  int quad = lane >> 4, l16 = lane & 15;
  int row0 = blockIdx.x * 16;

  int arow = row0 + l16;
  if (arow >= M) arow = M - 1;
  const float* Ap = A + (size_t)arow * K + quad * 8;
  const u16* Bpg = Bpk + (size_t)(wv * 64 + l16) * 32 + quad * 8;

  f32x4 acc[4];
  #pragma unroll
  for (int t = 0; t < 4; ++t) acc[t] = (f32x4){0.f, 0.f, 0.f, 0.f};

  union AF { bf16x8 v; u32 w[4]; };

  float4 ca0 = *reinterpret_cast<const float4*>(Ap);
  float4 ca1 = *reinterpret_cast<const float4*>(Ap + 4);
  bf16x8 cb0 = *reinterpret_cast<const bf16x8*>(Bpg);
  bf16x8 cb1 = *reinterpret_cast<const bf16x8*>(Bpg + 512);
  bf16x8 cb2 = *reinterpret_cast<const bf16x8*>(Bpg + 1024);
  bf16x8 cb3 = *reinterpret_cast<const bf16x8*>(Bpg + 1536);

  int nt = K >> 5;
  for (int kb = 0; kb < nt; ++kb) {
    int kn = (kb + 1 < nt) ? (kb + 1) : kb;
    float4 na0 = *reinterpret_cast<const float4*>(Ap + kn * 32);
    float4 na1 = *reinterpret_cast<const float4*>(Ap + kn * 32 + 4);
    const u16* bp = Bpg + (size_t)kn * 8192;
    bf16x8 nb0 = *reinterpret_cast<const bf16x8*>(bp);
    bf16x8 nb1 = *reinterpret_cast<const bf16x8*>(bp + 512);
    bf16x8 nb2 = *reinterpret_cast<const bf16x8*>(bp + 1024);
    bf16x8 nb3 = *reinterpret_cast<const bf16x8*>(bp + 1536);

    AF af;
    af.w[0] = (u32)f2bf_rne(ca0.x) | ((u32)f2bf_rne(ca0.y) << 16);
    af.w[1] = (u32)f2bf_rne(ca0.z) | ((u32)f2bf_rne(ca0.w) << 16);
    af.w[2] = (u32)f2bf_rne(ca1.x) | ((u32)f2bf_rne(ca1.y) << 16);
    af.w[3] = (u32)f2bf_rne(ca1.z) | ((u32)f2bf_rne(ca1.w) << 16);
    acc[0] = __builtin_amdgcn_mfma_f32_16x16x32_bf16(af.v, cb0, acc[0], 0, 0, 0);
    acc[1] = __builtin_amdgcn_mfma_f32_16x16x32_bf16(af.v, cb1, acc[1], 0, 0, 0);
    acc[2] = __builtin_amdgcn_mfma_f32_16x16x32_bf16(af.v, cb2, acc[2], 0, 0, 0);
    acc[3] = __builtin_amdgcn_mfma_f32_16x16x32_bf16(af.v, cb3, acc[3], 0, 0, 0);

    ca0 = na0; ca1 = na1;
    cb0 = nb0; cb1 = nb1; cb2 = nb2; cb3 = nb3;
  }

  u16* Pd = g.Pd[m];
  u16* Ps = g.Ps[m];
  float w2c[4];
  #pragma unroll
  for (int t = 0; t < 4; ++t) w2c[t] = w2[(wv & 1) * 64 + t * 16 + l16];

  float part[4];
  #pragma unroll
  for (int r = 0; r < 4; ++r) {
    int rr = row0 + quad * 4 + r;
    bool ok = rr < M;
    float qp = 0.f;
    #pragma unroll
    for (int t = 0; t < 4; ++t) {
      int c = (wv & 1) * 64 + t * 16 + l16;
      if (ok) {
        if (wv < 2) Pd[(size_t)rr * 128 + c] = f2bf_rne(acc[t][r]);
        else        Ps[(size_t)rr * 128 + c] = f2bf_rne(acc[t][r]);
      }
      qp += acc[t][r] * w2c[t];
    }
    #pragma unroll
    for (int mk = 1; mk < 16; mk <<= 1) qp += __shfl_xor(qp, mk, 64);
    part[r] = qp;
  }
  if (l16 == 0) {
    #pragma unroll
    for (int r = 0; r < 4; ++r) qpart[wv][quad * 4 + r] = part[r];
  }
  __syncthreads();
  if (tid < 32) {
    int row = tid & 15;
    int rr = row0 + row;
    if (rr < M) {
      if (tid < 16) g.qd[m][rr] = sane(qpart[0][row] + qpart[1][row]);
      else          g.qs[m][rr] = sane(qpart[2][row] + qpart[3][row]);
    }
  }
}

// fused 3-modality softmax+aggregate (unchanged from R9)
__global__ __launch_bounds__(256) void aggregate_all(AgArgs a) {
  int n = blockIdx.x * 4 + (threadIdx.x >> 6);
  if (n >= a.N) return;
  int lane = threadIdx.x & 63;
  int N = a.N, NR = a.NR, E = a.E;
  int eb = a.offs[n], ee = a.offs[n + 1];
  if (eb < 0) eb = 0;
  if (eb > E) eb = E;
  if (ee < eb) ee = eb;
  if (ee > E) ee = E;
  int En = ee - eb;

  float al = a.alphaP[0];
  if (!(al > 0.f && al < 1.f)) al = 0.1f;
  float ga = a.gammaP[0];
  if (!(ga > 0.f && ga < 1.f)) ga = 0.8f;
  float coef[3] = {1.f - al - ga, al, ga};

  float qdn[3];
  #pragma unroll
  for (int m = 0; m < 3; ++m) qdn[m] = sane(a.qd[m][n]);

  float mx[3] = {-1e30f, -1e30f, -1e30f};
  for (int i = lane; i < En; i += 64) {
    int e = iclamp(a.eid[eb + i], E);
    int s = iclamp(a.src[e], N);
    int t = iclamp(a.etyp[e], NR);
    #pragma unroll
    for (int m = 0; m < 3; ++m)
      mx[m] = fmaxf(mx[m], lrelu(qdn[m] + sane(a.qs[m][s]) + sane(a.qr[m][t])));
  }
  #pragma unroll
  for (int m = 0; m < 3; ++m) mx[m] = wred_max(mx[m]);

  float z[3] = {0.f, 0.f, 0.f};
  float a0[3] = {0.f, 0.f, 0.f};
  float a1[3] = {0.f, 0.f, 0.f};
  for (int c0 = 0; c0 < En; c0 += 64) {
    int cn = min(64, En - c0);
    float wr[3] = {0.f, 0.f, 0.f};
    int s = 0, t = 0;
    if (lane < cn) {
      int e = iclamp(a.eid[eb + c0 + lane], E);
      s = iclamp(a.src[e], N);
      t = iclamp(a.etyp[e], NR);
      #pragma unroll
      for (int m = 0; m < 3; ++m) {
        float b = lrelu(qdn[m] + sane(a.qs[m][s]) + sane(a.qr[m][t]));
        float arg = fmaxf(fminf(b - mx[m], 0.f), -80.f);
        wr[m] = __expf(arg);
      }
    }
    #pragma unroll
    for (int m = 0; m < 3; ++m) z[m] += wr[m];
    for (int j = 0; j < cn; ++j) {
      int sj = __shfl(s, j, 64);
      int tj = __shfl(t, j, 64);
      float w0 = __shfl(wr[0], j, 64);
      float w1 = __shfl(wr[1], j, 64);
      float w2 = __shfl(wr[2], j, 64);
      float wj[3] = {w0, w1, w2};
      #pragma unroll
      for (int m = 0; m < 3; ++m) {
        u32 pu = *reinterpret_cast<const u32*>(a.Ps[m] + (size_t)sj * 128 + 2 * lane);
        u32 ru = *reinterpret_cast<const u32*>(a.Pr[m] + (size_t)tj * 128 + 2 * lane);
        float ps0 = __uint_as_float(pu << 16), ps1 = __uint_as_float(pu & 0xffff0000u);
        float pr0 = __uint_as_float(ru << 16), pr1 = __uint_as_float(ru & 0xffff0000u);
        a0[m] = fmaf(wj[m], sane(ps0) + sane(pr0), a0[m]);
        a1[m] = fmaf(wj[m], sane(ps1) + sane(pr1), a1[m]);
      }
    }
  }
  #pragma unroll
  for (int m = 0; m < 3; ++m) z[m] = wred_sum(z[m]);

  float o0 = 0.f, o1 = 0.f;
  #pragma unroll
  for (int m = 0; m < 3; ++m) {
    float h0 = 0.f, h1 = 0.f;
    if (En > 0 && z[m] > 0.f) {
      float rz = 1.f / z[m];
      u32 du = *reinterpret_cast<const u32*>(a.Pd[m] + (size_t)n * 128 + 2 * lane);
      float pd0 = __uint_as_float(du << 16), pd1 = __uint_as_float(du & 0xffff0000u);
      h0 = lrelu(sane(pd0) + a0[m] * rz);
      h1 = lrelu(sane(pd1) + a1[m] * rz);
    }
    o0 = fmaf(coef[m], h0, o0);
    o1 = fmaf(coef[m], h1, o1);
  }
  float* op = a.outp + (size_t)n * 128 + 2 * lane;
  op[0] = sane(o0);
  op[1] = sane(o1);
}

// serial-path per-modality aggregate (R9, unchanged)
__global__ __launch_bounds__(256) void aggregate_m(
    const int* __restrict__ eid, const int* __restrict__ offs,
    const int* __restrict__ src, const int* __restrict__ etyp,
    const float* __restrict__ qd, const float* __restrict__ qs, const float* __restrict__ qr,
    const u16* __restrict__ Pd, const u16* __restrict__ Ps, const u16* __restrict__ Pr,
    const float* __restrict__ alphaP, const float* __restrict__ gammaP,
    int mIdx, int first,
    float* __restrict__ outp,
    int N, int NR, int E) {
  int n = blockIdx.x * 4 + (threadIdx.x >> 6);
  if (n >= N) return;
  int lane = threadIdx.x & 63;
  int eb = offs[n], ee = offs[n + 1];
  if (eb < 0) eb = 0;
  if (eb > E) eb = E;
  if (ee < eb) ee = eb;
  if (ee > E) ee = E;
  int En = ee - eb;

  float al = alphaP[0];
  if (!(al > 0.f && al < 1.f)) al = 0.1f;
  float ga = gammaP[0];
  if (!(ga > 0.f && ga < 1.f)) ga = 0.8f;
  float coef = (mIdx == 0) ? (1.f - al - ga) : (mIdx == 1 ? al : ga);

  float qdn = sane(qd[n]);
  float mx = -1e30f;
  for (int i = lane; i < En; i += 64) {
    int e = iclamp(eid[eb + i], E);
    int s = iclamp(src[e], N);
    int t = iclamp(etyp[e], NR);
    mx = fmaxf(mx, lrelu(qdn + sane(qs[s]) + sane(qr[t])));
  }
  mx = wred_max(mx);

  float z = 0.f, a0 = 0.f, a1 = 0.f;
  for (int c0 = 0; c0 < En; c0 += 64) {
    int cn = min(64, En - c0);
    float wraw = 0.f;
    int s = 0, t = 0;
    if (lane < cn) {
      int e = iclamp(eid[eb + c0 + lane], E);
      s = iclamp(src[e], N);
      t = iclamp(etyp[e], NR);
      float b = lrelu(qdn + sane(qs[s]) + sane(qr[t]));
      float arg = fmaxf(fminf(b - mx, 0.f), -80.f);
      wraw = __expf(arg);
    }
    z += wraw;
    for (int j = 0; j < cn; ++j) {
      float wj = __shfl(wraw, j, 64);
      int sj = __shfl(s, j, 64);
      int tj = __shfl(t, j, 64);
      u32 pu = *reinterpret_cast<const u32*>(Ps + (size_t)sj * 128 + 2 * lane);
      u32 ru = *reinterpret_cast<const u32*>(Pr + (size_t)tj * 128 + 2 * lane);
      float ps0 = __uint_as_float(pu << 16), ps1 = __uint_as_float(pu & 0xffff0000u);
      float pr0 = __uint_as_float(ru << 16), pr1 = __uint_as_float(ru & 0xffff0000u);
      a0 = fmaf(wj, sane(ps0) + sane(pr0), a0);
      a1 = fmaf(wj, sane(ps1) + sane(pr1), a1);
    }
  }
  z = wred_sum(z);

  float h0 = 0.f, h1 = 0.f;
  if (En > 0 && z > 0.f) {
    float rz = 1.f / z;
    u32 du = *reinterpret_cast<const u32*>(Pd + (size_t)n * 128 + 2 * lane);
    float pd0 = __uint_as_float(du << 16), pd1 = __uint_as_float(du & 0xffff0000u);
    h0 = lrelu(sane(pd0) + a0 * rz);
    h1 = lrelu(sane(pd1) + a1 * rz);
  }
  float c0v = sane(coef * h0);
  float c1v = sane(coef * h1);

  float* op = outp + (size_t)n * 128 + 2 * lane;
  if (first) { op[0] = c0v; op[1] = c1v; }
  else       { op[0] = sane(op[0]) + c0v; op[1] = sane(op[1]) + c1v; }
}

// serial per-modality prep (packed-B write)
__global__ void prep_wc2(const float* __restrict__ W1, const float* __restrict__ Wmod,
                         int K, int isCopy, u16* __restrict__ out) {
  int k = blockIdx.x * blockDim.x + threadIdx.x;
  int o = blockIdx.y;
  if (k >= K) return;
  int half = (o >= 128) ? 128 : 0;
  int oo = o & 127;
  float acc;
  if (isCopy) {
    acc = W1[oo * 384 + half + k];
  } else {
    acc = 0.f;
    for (int i = 0; i < 128; ++i)
      acc += W1[oo * 384 + half + i] * Wmod[i * K + k];
  }
  out[((size_t)(k >> 5) * 256 + o) * 32 + (k & 31)] = f2bf_rne(acc);
}

__global__ __launch_bounds__(128) void prep_pr_q(
    const float* __restrict__ rel, const float* __restrict__ W1,
    const float* __restrict__ b1, const float* __restrict__ bmod,
    const float* __restrict__ w2,
    u16* __restrict__ Pr, float* __restrict__ qr, int NR) {
  __shared__ float red[128];
  int r = blockIdx.x;
  if (r >= NR) return;
  int o = threadIdx.x;
  float acc = b1[o];
  for (int i = 0; i < 128; ++i)
    acc += W1[o * 384 + 256 + i] * rel[r * 128 + i];
  if (bmod != nullptr) {
    for (int i = 0; i < 128; ++i)
      acc += (W1[o * 384 + i] + W1[o * 384 + 128 + i]) * bmod[i];
  }
  Pr[(size_t)r * 128 + o] = f2bf_rne(acc);
  red[o] = acc * w2[o];
  __syncthreads();
  for (int s = 64; s > 0; s >>= 1) {
    if (o < s) red[o] += red[o + s];
    __syncthreads();
  }
  if (o == 0) qr[r] = sane(red[0]);
}

extern "C" void kernel_launch(void* const* d_in, const int* in_sizes, int n_in,
                              void* d_out, int out_size, void* d_ws, size_t ws_size,
                              hipStream_t stream) {
  const int* ei        = (const int*)d_in[1];
  const int* et        = (const int*)d_in[2];
  const float* visual  = (const float*)d_in[3];
  const float* textual = (const float*)d_in[4];
  const float* semb    = (const float*)d_in[5];
  const float* relemb  = (const float*)d_in[6];
  const float* W1s = (const float*)d_in[7];
  const float* b1s = (const float*)d_in[8];
  const float* w2s = (const float*)d_in[9];
  const float* W1v = (const float*)d_in[10];
  const float* b1v = (const float*)d_in[11];
  const float* w2v = (const float*)d_in[12];
  const float* W1t = (const float*)d_in[13];
  const float* b1t = (const float*)d_in[14];
  const float* w2t = (const float*)d_in[15];
  const float* Wv  = (const float*)d_in[16];
  const float* bv  = (const float*)d_in[17];
  const float* Wt  = (const float*)d_in[18];
  const float* bt  = (const float*)d_in[19];
  const float* alphaP = (const float*)d_in[20];
  const float* gammaP = (const float*)d_in[21];
  float* outp = (float*)d_out;

  const int E   = in_sizes[2];
  const int N   = in_sizes[5] / DIM;
  const int NR  = in_sizes[6] / DIM;
  const int VIS = in_sizes[3] / N;   // 512
  const int TXT = in_sizes[4] / N;   // 768
  const int KMAX = (TXT > VIS) ? TXT : VIS;
  int Ks[3] = {DIM, VIS, TXT};
  const int NT16 = (N + 15) / 16;
  const size_t Npad = (size_t)NT16 * 16;

  const float* W1a[3]   = {W1s, W1v, W1t};
  const float* b1a[3]   = {b1s, b1v, b1t};
  const float* w2a[3]   = {w2s, w2v, w2t};
  const float* Wmoda[3] = {nullptr, Wv, Wt};
  const float* bmoda[3] = {nullptr, bv, bt};
  const float* Amoda[3] = {semb, visual, textual};

  const int* esrc = ei;
  const int* edst = ei + E;
  int egrid = (E + 255) / 256;

  size_t off = 0;
  auto take = [&](size_t bytes) -> size_t {
    size_t o = off;
    off = (off + bytes + 255) & ~(size_t)255;
    return o;
  };
  // ---- shared head ----
  size_t o_cnt  = take((size_t)2 * N * 4);
  size_t o_offs = take((size_t)(N + 1) * 4);
  size_t o_eid  = take((size_t)E * 4);
  // ---- fused tables ----
  size_t o_qdm[3], o_qsm[3], o_qrm[3], o_Prm[3], o_Wcm[3], o_Pdm[3], o_Psm[3];
  for (int m = 0; m < 3; ++m) {
    o_qdm[m] = take((size_t)N * 4);
    o_qsm[m] = take((size_t)N * 4);
    o_qrm[m] = take((size_t)NR * 4);
    o_Prm[m] = take((size_t)NR * 128 * 2);
    o_Wcm[m] = take((size_t)256 * Ks[m] * 2);
    o_Pdm[m] = take((size_t)N * 128 * 2);
    o_Psm[m] = take((size_t)N * 128 * 2);
  }
  size_t need_fused = off;                      // ~18 MB (P2)
  size_t o_Apk[3];
  for (int m = 0; m < 3; ++m) o_Apk[m] = take(Npad * Ks[m] * 2);
  size_t need_packed = off;                     // ~47 MB (P1)

  // ---- serial layout ----
  off = 0;
  size_t s_cnt  = take((size_t)2 * N * 4);
  size_t s_offs = take((size_t)(N + 1) * 4);
  size_t s_eid  = take((size_t)E * 4);
  size_t s_qd   = take((size_t)N * 4);
  size_t s_qs   = take((size_t)N * 4);
  size_t s_qr   = take((size_t)NR * 4);
  size_t s_Pr   = take((size_t)NR * 128 * 2);
  size_t s_Wc   = take((size_t)256 * KMAX * 2);
  size_t s_Pd   = take((size_t)N * 128 * 2);
  size_t s_Ps   = take((size_t)N * 128 * 2);
  size_t need_serial = off;

  char* w = (char*)d_ws;

  if (ws_size >= need_fused) {
    bool packed = (ws_size >= need_packed);

    int* counts = (int*)(w + o_cnt);
    int* cursor = counts + N;
    int* offs   = (int*)(w + o_offs);
    int* eid    = (int*)(w + o_eid);

    hipMemsetAsync(counts, 0, (size_t)2 * N * 4, stream);
    hipMemsetAsync(eid, 0, (size_t)E * 4, stream);
    hist_k<<<egrid, 256, 0, stream>>>(edst, counts, E, N);
    scan_k<<<1, 1024, 0, stream>>>(counts, offs, N);
    scatter_k<<<egrid, 256, 0, stream>>>(edst, offs, cursor, eid, E, N);

    PrepArgs pa;
    PrArgs ra;
    AgArgs aa;
    ra.rel = relemb; ra.NR = NR;
    for (int m = 0; m < 3; ++m) {
      pa.W1[m] = W1a[m]; pa.Wmod[m] = Wmoda[m]; pa.K[m] = Ks[m];
      pa.isCopy[m] = (m == 0);
      pa.Wc[m] = (u16*)(w + o_Wcm[m]);
      ra.W1[m] = W1a[m]; ra.b1[m] = b1a[m]; ra.bmod[m] = bmoda[m]; ra.w2[m] = w2a[m];
      ra.Pr[m] = (u16*)(w + o_Prm[m]); ra.qr[m] = (float*)(w + o_qrm[m]);
      aa.qd[m] = (const float*)(w + o_qdm[m]);
      aa.qs[m] = (const float*)(w + o_qsm[m]);
      aa.qr[m] = (const float*)(w + o_qrm[m]);
      aa.Pd[m] = (const u16*)(w + o_Pdm[m]);
      aa.Ps[m] = (const u16*)(w + o_Psm[m]);
      aa.Pr[m] = (const u16*)(w + o_Prm[m]);
    }
    aa.eid = eid; aa.offs = offs; aa.src = esrc; aa.etyp = et;
    aa.alphaP = alphaP; aa.gammaP = gammaP;
    aa.outp = outp; aa.N = N; aa.NR = NR; aa.E = E;

    prep_wc_all<<<dim3((KMAX + 255) / 256, 256, 3), 256, 0, stream>>>(pa);
    prep_pr_all<<<dim3(NR, 1, 3), 128, 0, stream>>>(ra);

    if (packed) {
      CArgs ca;
      GpArgs gp;
      gp.M = N;
      for (int m = 0; m < 3; ++m) {
        ca.A[m] = Amoda[m]; ca.Ap[m] = (u16*)(w + o_Apk[m]); ca.K[m] = Ks[m];
        gp.Ap[m] = (const u16*)(w + o_Apk[m]);
        gp.B[m] = (const u16*)(w + o_Wcm[m]);
        gp.w2[m] = w2a[m];
        gp.Pd[m] = (u16*)(w + o_Pdm[m]); gp.Ps[m] = (u16*)(w + o_Psm[m]);
        gp.qd[m] = (float*)(w + o_qdm[m]); gp.qs[m] = (float*)(w + o_qsm[m]);
        gp.K[m] = Ks[m];
      }
      ca.M = N;
      convertA<<<dim3(NT16, 3), 256, 0, stream>>>(ca);
      gemm_pk<<<dim3(NT16, 3), 256, 0, stream>>>(gp);
    } else {
      GArgs ga;
      ga.M = N;
      for (int m = 0; m < 3; ++m) {
        ga.A[m] = Amoda[m]; ga.B[m] = (const u16*)(w + o_Wcm[m]); ga.w2[m] = w2a[m];
        ga.Pd[m] = (u16*)(w + o_Pdm[m]); ga.Ps[m] = (u16*)(w + o_Psm[m]);
        ga.qd[m] = (float*)(w + o_qdm[m]); ga.qs[m] = (float*)(w + o_qsm[m]);
        ga.K[m] = Ks[m];
      }
      gemm_all<<<dim3(NT16, 3), 256, 0, stream>>>(ga);
    }

    aggregate_all<<<(N + 3) / 4, 256, 0, stream>>>(aa);
    return;
  }

  if (ws_size < need_serial) {
    hipMemsetAsync(d_out, 0, (size_t)out_size * 4, stream);  // finite diagnostic
    return;
  }

  // =========== SERIAL FALLBACK ===========
  int* counts = (int*)(w + s_cnt);
  int* cursor = counts + N;
  int* offs   = (int*)(w + s_offs);
  int* eid    = (int*)(w + s_eid);
  float* qd   = (float*)(w + s_qd);
  float* qs   = (float*)(w + s_qs);
  float* qr   = (float*)(w + s_qr);
  u16* Pr     = (u16*)(w + s_Pr);
  u16* Wc     = (u16*)(w + s_Wc);
  u16* Pd     = (u16*)(w + s_Pd);
  u16* Ps     = (u16*)(w + s_Ps);

  hipMemsetAsync(counts, 0, (size_t)2 * N * 4, stream);
  hipMemsetAsync(eid, 0, (size_t)E * 4, stream);
  hist_k<<<egrid, 256, 0, stream>>>(edst, counts, E, N);
  scan_k<<<1, 1024, 0, stream>>>(counts, offs, N);
  scatter_k<<<egrid, 256, 0, stream>>>(edst, offs, cursor, eid, E, N);

  for (int m = 0; m < 3; ++m) {
    prep_wc2<<<dim3((Ks[m] + 255) / 256, 256), 256, 0, stream>>>(
        W1a[m], Wmoda[m], Ks[m], (m == 0) ? 1 : 0, Wc);
    prep_pr_q<<<NR, 128, 0, stream>>>(relemb, W1a[m], b1a[m], bmoda[m], w2a[m], Pr, qr, NR);

    GArgs ga;
    ga.A[0] = Amoda[m]; ga.B[0] = Wc; ga.w2[0] = w2a[m];
    ga.Pd[0] = Pd; ga.Ps[0] = Ps; ga.qd[0] = qd; ga.qs[0] = qs;
    ga.M = N; ga.K[0] = Ks[m];
    gemm_all<<<dim3(NT16, 1), 256, 0, stream>>>(ga);

    aggregate_m<<<(N + 3) / 4, 256, 0, stream>>>(eid, offs, esrc, et,
                                                 qd, qs, qr, Pd, Ps, Pr,
                                                 alphaP, gammaP, m, (m == 0) ? 1 : 0,
                                                 outp, N, NR, E);
  }
}

// Round 11
// 303.826 us; speedup vs baseline: 1.4717x; 1.0890x over previous
//
#include <hip/hip_runtime.h>
#include <hip/hip_bf16.h>

typedef unsigned short u16;
typedef unsigned int u32;
typedef __bf16 bf16x8 __attribute__((ext_vector_type(8)));
typedef float f32x4 __attribute__((ext_vector_type(4)));

#define DIM 128
#define NTMAX 24   // max K/32 (TXT=768)

__device__ __forceinline__ u16 f2bf_rne(float x) {
  u32 u = __float_as_uint(x);
  return (u16)((u + 0x7fffu + ((u >> 16) & 1u)) >> 16);
}
__device__ __forceinline__ float lrelu(float x) { return x > 0.f ? x : 0.01f * x; }
__device__ __forceinline__ int iclamp(int v, int hi) { return v < 0 ? 0 : (v >= hi ? hi - 1 : v); }
__device__ __forceinline__ float sane(float x) { return (x == x) ? x : 0.f; }

__device__ __forceinline__ float wred_max(float v) {
  #pragma unroll
  for (int o = 32; o > 0; o >>= 1) v = fmaxf(v, __shfl_xor(v, o, 64));
  return v;
}
__device__ __forceinline__ float wred_sum(float v) {
  #pragma unroll
  for (int o = 32; o > 0; o >>= 1) v += __shfl_xor(v, o, 64);
  return v;
}

// ---------------- CSR build ----------------
__global__ void hist_k(const int* __restrict__ dst, int* __restrict__ cnt, int E, int N) {
  int e = blockIdx.x * blockDim.x + threadIdx.x;
  if (e < E) {
    int d = dst[e];
    if (d >= 0 && d < N) atomicAdd(&cnt[d], 1);
  }
}

__global__ __launch_bounds__(1024) void scan_k(const int* __restrict__ cnt,
                                               int* __restrict__ offs, int N) {
  __shared__ int sums[1024];
  int t = threadIdx.x;
  int chunk = (N + 1023) >> 10;
  int base = t * chunk;
  int s = 0;
  for (int i = 0; i < chunk; ++i) { int idx = base + i; if (idx < N) s += cnt[idx]; }
  sums[t] = s;
  __syncthreads();
  for (int off = 1; off < 1024; off <<= 1) {
    int v = (t >= off) ? sums[t - off] : 0;
    __syncthreads();
    sums[t] += v;
    __syncthreads();
  }
  int prefix = (t > 0) ? sums[t - 1] : 0;
  for (int i = 0; i < chunk; ++i) {
    int idx = base + i;
    if (idx < N) { offs[idx] = prefix; prefix += cnt[idx]; }
  }
  if (t == 1023) offs[N] = sums[1023];
}

__global__ void scatter_k(const int* __restrict__ dst, const int* __restrict__ offs,
                          int* __restrict__ cursor, int* __restrict__ eid, int E, int N) {
  int e = blockIdx.x * blockDim.x + threadIdx.x;
  if (e < E) {
    int d = dst[e];
    if (d >= 0 && d < N) {
      int pos = offs[d] + atomicAdd(&cursor[d], 1);
      if (pos >= 0 && pos < E) eid[pos] = e;
    }
  }
}

// ================= structs =================
struct PrepArgs {
  const float* W1[3]; const float* Wmod[3]; int K[3]; int isCopy[3];
  u16* Wc[3];
};
struct PrArgs {
  const float* rel; const float* W1[3]; const float* b1[3];
  const float* bmod[3]; const float* w2[3];
  u16* PrAll; float* qr[3]; int NR;
};
struct GArgs {
  const float* A[3]; const u16* B[3]; const float* w2[3];
  u16* PdAll; u16* PsAll; float* qd[3]; float* qs[3];
  int M; int K[3];
};
struct AgArgs {
  const int* eid; const int* offs; const int* src; const int* etyp;
  const float* qd[3]; const float* qs[3]; const float* qr[3];
  const u16* PdAll; const u16* PsAll; const u16* PrAll;
  const float* alphaP; const float* gammaP;
  float* outp; int N; int NR; int E;
};

// combined bf16 B, PACKED trip-major: Wc[((k>>5)*256 + o)*32 + (k&31)]
__global__ void prep_wc_all(PrepArgs a) {
  int m = blockIdx.z;
  int K = a.K[m];
  int k = blockIdx.x * blockDim.x + threadIdx.x;
  int o = blockIdx.y;                       // 0..255
  if (k >= K) return;
  int half = (o >= 128) ? 128 : 0;
  int oo = o & 127;
  const float* W1 = a.W1[m];
  float acc;
  if (a.isCopy[m]) {
    acc = W1[oo * 384 + half + k];
  } else {
    const float* Wm = a.Wmod[m];
    acc = 0.f;
    for (int i = 0; i < 128; ++i)
      acc += W1[oo * 384 + half + i] * Wm[i * K + k];
  }
  a.Wc[m][((size_t)(k >> 5) * 256 + o) * 32 + (k & 31)] = f2bf_rne(acc);
}

// PrAll[r][m*128+o] (bf16, interleaved) + qr[m][r] (f32); grid (NR,1,3)
__global__ __launch_bounds__(128) void prep_pr_all(PrArgs a) {
  __shared__ float red[128];
  int m = blockIdx.z;
  int r = blockIdx.x;
  if (r >= a.NR) return;
  int o = threadIdx.x;
  const float* W1 = a.W1[m];
  float acc = a.b1[m][o];
  for (int i = 0; i < 128; ++i)
    acc += W1[o * 384 + 256 + i] * a.rel[r * 128 + i];
  const float* bmod = a.bmod[m];
  if (bmod != nullptr) {
    for (int i = 0; i < 128; ++i)
      acc += (W1[o * 384 + i] + W1[o * 384 + 128 + i]) * bmod[i];
  }
  a.PrAll[(size_t)r * 384 + m * 128 + o] = f2bf_rne(acc);
  red[o] = acc * a.w2[m][o];
  __syncthreads();
  for (int s = 64; s > 0; s >>= 1) {
    if (o < s) red[o] += red[o + s];
    __syncthreads();
  }
  if (o == 0) a.qr[m][r] = sane(red[0]);
}

// ---------- fused convert+GEMM: A f32 → LDS bf16 (one barrier), then
// barrier-free MFMA K-loop with contiguous packed-B loads.
// grid (M/16, 3), 256 thr; wave wv: 16 rows × cols wv*64..+64.
// Tables written INTERLEAVED: P[node][m*128 + dim] (bf16).
// C/D layout (verified): col = lane&15, row = (lane>>4)*4 + reg
__global__ __launch_bounds__(256) void gemm_fused(GArgs g) {
  __shared__ u16 Als[NTMAX * 16 * 32];   // ≤24 KB
  __shared__ float qpart[4][16];
  int m = blockIdx.y;
  int M = g.M, K = g.K[m];
  int nt = K >> 5;                        // 4 / 16 / 24 (even)
  const u16* Bpk = g.B[m];
  const float* w2 = g.w2[m];
  int tid = threadIdx.x;
  int lane = tid & 63, wv = tid >> 6;
  int quad = lane >> 4, l16 = lane & 15;
  int row0 = blockIdx.x * 16;

  // stage A → LDS (packed trip-major): thread t → row t>>4, 2 f32 at (t&15)*2
  {
    int srow = tid >> 4;
    int scol = (tid & 15) * 2;
    int gr = row0 + srow;
    bool v = gr < M;
    const float* Ag = g.A[m] + (size_t)(v ? gr : 0) * K;
    for (int kb = 0; kb < nt; ++kb) {
      float2 x = make_float2(0.f, 0.f);
      if (v) x = *reinterpret_cast<const float2*>(Ag + kb * 32 + scol);
      *reinterpret_cast<u32*>(&Als[(kb * 16 + srow) * 32 + scol]) =
          (u32)f2bf_rne(x.x) | ((u32)f2bf_rne(x.y) << 16);
    }
  }
  __syncthreads();

  const u16* Bpg = Bpk + (size_t)(wv * 64 + l16) * 32 + quad * 8;

  f32x4 acc[4];
  #pragma unroll
  for (int t = 0; t < 4; ++t) acc[t] = (f32x4){0.f, 0.f, 0.f, 0.f};

  for (int kb = 0; kb < nt; kb += 2) {
    bf16x8 a0 = *reinterpret_cast<const bf16x8*>(&Als[(kb * 16 + l16) * 32 + quad * 8]);
    bf16x8 a1 = *reinterpret_cast<const bf16x8*>(&Als[((kb + 1) * 16 + l16) * 32 + quad * 8]);
    const u16* b0p = Bpg + (size_t)kb * 8192;
    bf16x8 b00 = *reinterpret_cast<const bf16x8*>(b0p);
    bf16x8 b01 = *reinterpret_cast<const bf16x8*>(b0p + 512);
    bf16x8 b02 = *reinterpret_cast<const bf16x8*>(b0p + 1024);
    bf16x8 b03 = *reinterpret_cast<const bf16x8*>(b0p + 1536);
    const u16* b1p = b0p + 8192;
    bf16x8 b10 = *reinterpret_cast<const bf16x8*>(b1p);
    bf16x8 b11 = *reinterpret_cast<const bf16x8*>(b1p + 512);
    bf16x8 b12 = *reinterpret_cast<const bf16x8*>(b1p + 1024);
    bf16x8 b13 = *reinterpret_cast<const bf16x8*>(b1p + 1536);

    acc[0] = __builtin_amdgcn_mfma_f32_16x16x32_bf16(a0, b00, acc[0], 0, 0, 0);
    acc[1] = __builtin_amdgcn_mfma_f32_16x16x32_bf16(a0, b01, acc[1], 0, 0, 0);
    acc[2] = __builtin_amdgcn_mfma_f32_16x16x32_bf16(a0, b02, acc[2], 0, 0, 0);
    acc[3] = __builtin_amdgcn_mfma_f32_16x16x32_bf16(a0, b03, acc[3], 0, 0, 0);
    acc[0] = __builtin_amdgcn_mfma_f32_16x16x32_bf16(a1, b10, acc[0], 0, 0, 0);
    acc[1] = __builtin_amdgcn_mfma_f32_16x16x32_bf16(a1, b11, acc[1], 0, 0, 0);
    acc[2] = __builtin_amdgcn_mfma_f32_16x16x32_bf16(a1, b12, acc[2], 0, 0, 0);
    acc[3] = __builtin_amdgcn_mfma_f32_16x16x32_bf16(a1, b13, acc[3], 0, 0, 0);
  }

  // epilogue: interleaved table stores + fused q
  u16* PdAll = g.PdAll;
  u16* PsAll = g.PsAll;
  float w2c[4];
  #pragma unroll
  for (int t = 0; t < 4; ++t) w2c[t] = w2[(wv & 1) * 64 + t * 16 + l16];

  float part[4];
  #pragma unroll
  for (int r = 0; r < 4; ++r) {
    int rr = row0 + quad * 4 + r;
    bool ok = rr < M;
    float qp = 0.f;
    #pragma unroll
    for (int t = 0; t < 4; ++t) {
      int c = (wv & 1) * 64 + t * 16 + l16;
      if (ok) {
        if (wv < 2) PdAll[(size_t)rr * 384 + m * 128 + c] = f2bf_rne(acc[t][r]);
        else        PsAll[(size_t)rr * 384 + m * 128 + c] = f2bf_rne(acc[t][r]);
      }
      qp += acc[t][r] * w2c[t];
    }
    #pragma unroll
    for (int mk = 1; mk < 16; mk <<= 1) qp += __shfl_xor(qp, mk, 64);
    part[r] = qp;
  }
  if (l16 == 0) {
    #pragma unroll
    for (int r = 0; r < 4; ++r) qpart[wv][quad * 4 + r] = part[r];
  }
  __syncthreads();
  if (tid < 32) {
    int row = tid & 15;
    int rr = row0 + row;
    if (rr < M) {
      if (tid < 16) g.qd[m][rr] = sane(qpart[0][row] + qpart[1][row]);
      else          g.qs[m][rr] = sane(qpart[2][row] + qpart[3][row]);
    }
  }
}

// fused 3-modality softmax+aggregate; interleaved tables, lean j-loop
__global__ __launch_bounds__(256) void aggregate_all(AgArgs a) {
  int n = blockIdx.x * 4 + (threadIdx.x >> 6);
  if (n >= a.N) return;
  int lane = threadIdx.x & 63;
  int N = a.N, NR = a.NR, E = a.E;
  int eb = a.offs[n], ee = a.offs[n + 1];
  if (eb < 0) eb = 0;
  if (eb > E) eb = E;
  if (ee < eb) ee = eb;
  if (ee > E) ee = E;
  int En = ee - eb;

  float al = a.alphaP[0];
  if (!(al > 0.f && al < 1.f)) al = 0.1f;
  float ga = a.gammaP[0];
  if (!(ga > 0.f && ga < 1.f)) ga = 0.8f;
  float coef[3] = {1.f - al - ga, al, ga};

  float qdn[3];
  #pragma unroll
  for (int m = 0; m < 3; ++m) qdn[m] = sane(a.qd[m][n]);

  // pass 1: segment max per modality (lane-parallel over edges — cheap)
  float mx[3] = {-1e30f, -1e30f, -1e30f};
  for (int i = lane; i < En; i += 64) {
    int e = iclamp(a.eid[eb + i], E);
    int s = iclamp(a.src[e], N);
    int t = iclamp(a.etyp[e], NR);
    #pragma unroll
    for (int m = 0; m < 3; ++m)
      mx[m] = fmaxf(mx[m], lrelu(qdn[m] + a.qs[m][s] + a.qr[m][t]));
  }
  #pragma unroll
  for (int m = 0; m < 3; ++m) mx[m] = wred_max(mx[m]);

  const u16* PsAll = a.PsAll;
  const u16* PrAll = a.PrAll;
  int dlo = 2 * lane;   // this lane's dim pair

  // pass 2: z + unnormalized accumulation
  float z[3] = {0.f, 0.f, 0.f};
  float a0[3] = {0.f, 0.f, 0.f};
  float a1[3] = {0.f, 0.f, 0.f};
  for (int c0 = 0; c0 < En; c0 += 64) {
    int cn = min(64, En - c0);
    float wr[3] = {0.f, 0.f, 0.f};
    int s = 0, t = 0;
    if (lane < cn) {
      int e = iclamp(a.eid[eb + c0 + lane], E);
      s = iclamp(a.src[e], N);
      t = iclamp(a.etyp[e], NR);
      #pragma unroll
      for (int m = 0; m < 3; ++m) {
        float b = lrelu(qdn[m] + a.qs[m][s] + a.qr[m][t]);
        float arg = fmaxf(fminf(b - mx[m], 0.f), -80.f);
        wr[m] = __expf(arg);
      }
    }
    #pragma unroll
    for (int m = 0; m < 3; ++m) z[m] += wr[m];
    for (int j = 0; j < cn; ++j) {
      int sj = __shfl(s, j, 64);
      int tj = __shfl(t, j, 64);
      float w0 = __shfl(wr[0], j, 64);
      float w1 = __shfl(wr[1], j, 64);
      float w2 = __shfl(wr[2], j, 64);
      float wj[3] = {w0, w1, w2};
      const u16* ps = PsAll + (size_t)sj * 384 + dlo;
      const u16* pr = PrAll + (size_t)tj * 384 + dlo;
      #pragma unroll
      for (int m = 0; m < 3; ++m) {
        u32 pu = *reinterpret_cast<const u32*>(ps + m * 128);
        u32 ru = *reinterpret_cast<const u32*>(pr + m * 128);
        float ps0 = __uint_as_float(pu << 16), ps1 = __uint_as_float(pu & 0xffff0000u);
        float pr0 = __uint_as_float(ru << 16), pr1 = __uint_as_float(ru & 0xffff0000u);
        a0[m] = fmaf(wj[m], ps0 + pr0, a0[m]);
        a1[m] = fmaf(wj[m], ps1 + pr1, a1[m]);
      }
    }
  }
  #pragma unroll
  for (int m = 0; m < 3; ++m) z[m] = wred_sum(z[m]);

  float o0 = 0.f, o1 = 0.f;
  const u16* pd = a.PdAll + (size_t)n * 384 + dlo;
  #pragma unroll
  for (int m = 0; m < 3; ++m) {
    float h0 = 0.f, h1 = 0.f;
    if (En > 0 && z[m] > 0.f) {
      float rz = 1.f / z[m];
      u32 du = *reinterpret_cast<const u32*>(pd + m * 128);
      float pd0 = __uint_as_float(du << 16), pd1 = __uint_as_float(du & 0xffff0000u);
      h0 = lrelu(pd0 + a0[m] * rz);
      h1 = lrelu(pd1 + a1[m] * rz);
    }
    o0 = fmaf(coef[m], h0, o0);
    o1 = fmaf(coef[m], h1, o1);
  }
  float* op = a.outp + (size_t)n * 128 + dlo;
  op[0] = sane(o0);
  op[1] = sane(o1);
}

extern "C" void kernel_launch(void* const* d_in, const int* in_sizes, int n_in,
                              void* d_out, int out_size, void* d_ws, size_t ws_size,
                              hipStream_t stream) {
  const int* ei        = (const int*)d_in[1];
  const int* et        = (const int*)d_in[2];
  const float* visual  = (const float*)d_in[3];
  const float* textual = (const float*)d_in[4];
  const float* semb    = (const float*)d_in[5];
  const float* relemb  = (const float*)d_in[6];
  const float* W1s = (const float*)d_in[7];
  const float* b1s = (const float*)d_in[8];
  const float* w2s = (const float*)d_in[9];
  const float* W1v = (const float*)d_in[10];
  const float* b1v = (const float*)d_in[11];
  const float* w2v = (const float*)d_in[12];
  const float* W1t = (const float*)d_in[13];
  const float* b1t = (const float*)d_in[14];
  const float* w2t = (const float*)d_in[15];
  const float* Wv  = (const float*)d_in[16];
  const float* bv  = (const float*)d_in[17];
  const float* Wt  = (const float*)d_in[18];
  const float* bt  = (const float*)d_in[19];
  const float* alphaP = (const float*)d_in[20];
  const float* gammaP = (const float*)d_in[21];
  float* outp = (float*)d_out;

  const int E   = in_sizes[2];
  const int N   = in_sizes[5] / DIM;
  const int NR  = in_sizes[6] / DIM;
  const int VIS = in_sizes[3] / N;   // 512
  const int TXT = in_sizes[4] / N;   // 768
  const int KMAX = (TXT > VIS) ? TXT : VIS;
  int Ks[3] = {DIM, VIS, TXT};
  const int NT16 = (N + 15) / 16;

  const float* W1a[3]   = {W1s, W1v, W1t};
  const float* b1a[3]   = {b1s, b1v, b1t};
  const float* w2a[3]   = {w2s, w2v, w2t};
  const float* Wmoda[3] = {nullptr, Wv, Wt};
  const float* bmoda[3] = {nullptr, bv, bt};
  const float* Amoda[3] = {semb, visual, textual};

  const int* esrc = ei;
  const int* edst = ei + E;
  int egrid = (E + 255) / 256;

  size_t off = 0;
  auto take = [&](size_t bytes) -> size_t {
    size_t o = off;
    off = (off + bytes + 255) & ~(size_t)255;
    return o;
  };
  size_t o_cnt  = take((size_t)2 * N * 4);
  size_t o_offs = take((size_t)(N + 1) * 4);
  size_t o_eid  = take((size_t)E * 4);
  size_t o_qdm[3], o_qsm[3], o_qrm[3], o_Wcm[3];
  for (int m = 0; m < 3; ++m) {
    o_qdm[m] = take((size_t)N * 4);
    o_qsm[m] = take((size_t)N * 4);
    o_qrm[m] = take((size_t)NR * 4);
    o_Wcm[m] = take((size_t)256 * Ks[m] * 2);
  }
  size_t o_PrAll = take((size_t)NR * 384 * 2);
  size_t o_PdAll = take((size_t)N * 384 * 2);
  size_t o_PsAll = take((size_t)N * 384 * 2);
  size_t need = off;                           // ~17.5 MB (ws proven ≥ 47 MB)

  if (ws_size < need) {
    hipMemsetAsync(d_out, 0, (size_t)out_size * 4, stream);  // finite diagnostic
    return;
  }

  char* w = (char*)d_ws;
  int* counts = (int*)(w + o_cnt);
  int* cursor = counts + N;
  int* offs   = (int*)(w + o_offs);
  int* eid    = (int*)(w + o_eid);

  hipMemsetAsync(counts, 0, (size_t)2 * N * 4, stream);
  hipMemsetAsync(eid, 0, (size_t)E * 4, stream);
  hist_k<<<egrid, 256, 0, stream>>>(edst, counts, E, N);
  scan_k<<<1, 1024, 0, stream>>>(counts, offs, N);
  scatter_k<<<egrid, 256, 0, stream>>>(edst, offs, cursor, eid, E, N);

  PrepArgs pa;
  PrArgs ra;
  GArgs ga;
  AgArgs aa;
  ra.rel = relemb; ra.NR = NR;
  ra.PrAll = (u16*)(w + o_PrAll);
  ga.M = N;
  ga.PdAll = (u16*)(w + o_PdAll);
  ga.PsAll = (u16*)(w + o_PsAll);
  for (int m = 0; m < 3; ++m) {
    pa.W1[m] = W1a[m]; pa.Wmod[m] = Wmoda[m]; pa.K[m] = Ks[m];
    pa.isCopy[m] = (m == 0);
    pa.Wc[m] = (u16*)(w + o_Wcm[m]);
    ra.W1[m] = W1a[m]; ra.b1[m] = b1a[m]; ra.bmod[m] = bmoda[m]; ra.w2[m] = w2a[m];
    ra.qr[m] = (float*)(w + o_qrm[m]);
    ga.A[m] = Amoda[m]; ga.B[m] = (const u16*)(w + o_Wcm[m]); ga.w2[m] = w2a[m];
    ga.qd[m] = (float*)(w + o_qdm[m]); ga.qs[m] = (float*)(w + o_qsm[m]);
    ga.K[m] = Ks[m];
    aa.qd[m] = (const float*)(w + o_qdm[m]);
    aa.qs[m] = (const float*)(w + o_qsm[m]);
    aa.qr[m] = (const float*)(w + o_qrm[m]);
  }
  aa.PdAll = (const u16*)(w + o_PdAll);
  aa.PsAll = (const u16*)(w + o_PsAll);
  aa.PrAll = (const u16*)(w + o_PrAll);
  aa.eid = eid; aa.offs = offs; aa.src = esrc; aa.etyp = et;
  aa.alphaP = alphaP; aa.gammaP = gammaP;
  aa.outp = outp; aa.N = N; aa.NR = NR; aa.E = E;

  prep_wc_all<<<dim3((KMAX + 255) / 256, 256, 3), 256, 0, stream>>>(pa);
  prep_pr_all<<<dim3(NR, 1, 3), 128, 0, stream>>>(ra);
  gemm_fused<<<dim3(NT16, 3), 256, 0, stream>>>(ga);
  aggregate_all<<<(N + 3) / 4, 256, 0, stream>>>(aa);
}